// Round 13
// baseline (1136.068 us; speedup 1.0000x reference)
//
#include <hip/hip_runtime.h>
#include <cstddef>

// Problem constants
#define BATCH 8
#define LSEQ 1024
#define DMODEL 512
#define DINNER 1024
#define DSTATE 16
#define DTRANK 32
#define NHEAD 8
#define DHEAD 64
#define DFF 2048
#define MTOK 8192   // BATCH*LSEQ
#define NCHUNK 16
#define CLEN 64     // LSEQ / NCHUNK

typedef __attribute__((ext_vector_type(8))) short bfrag;          // 8 bf16 = 16 B
typedef __attribute__((ext_vector_type(4))) float f32x4;          // MFMA acc
typedef __attribute__((ext_vector_type(4))) unsigned short us4;
typedef unsigned short ushort_t;

__device__ __forceinline__ float silu_f(float x) { return x / (1.f + __expf(-x)); }

__device__ __forceinline__ unsigned short f2bf(float f) {  // RNE fp32->bf16
  unsigned u = __float_as_uint(f);
  return (unsigned short)((u + 0x7FFFu + ((u >> 16) & 1u)) >> 16);
}
__device__ __forceinline__ float bf2f(ushort_t u) {
  return __uint_as_float((unsigned)u << 16);
}

// async global->LDS, 16B per lane. LDS dest = wave-uniform base + lane*16.
__device__ __forceinline__ void gll16(const ushort_t* g, ushort_t* l) {
  __builtin_amdgcn_global_load_lds(
      (const __attribute__((address_space(1))) unsigned int*)g,
      (__attribute__((address_space(3))) unsigned int*)l, 16, 0, 0);
}

// ---------------------------------------------------------------------------
// 8-segment fp32 -> bf16 weight convert (single launch).
// ---------------------------------------------------------------------------
struct Cvt8Args {
  const float* s[8];
  ushort_t* d[8];
  int end[8];   // prefix-sum of blocks
};
__global__ __launch_bounds__(256) void cvt8(Cvt8Args a) {
  int blk = blockIdx.x;
  int seg = 0, start = 0;
#pragma unroll
  for (int i = 0; i < 7; ++i)
    if (blk >= a.end[i]) { seg = i + 1; start = a.end[i]; }
  int i4 = (blk - start) * 256 + threadIdx.x;
  float4 v = ((const float4*)a.s[seg])[i4];
  us4 o = {f2bf(v.x), f2bf(v.y), f2bf(v.z), f2bf(v.w)};
  ((us4*)a.d[seg])[i4] = o;
}

// ---------------------------------------------------------------------------
// Input projection: h[b,l,d] = sum_c x[b,c,l] * pw[d,c] + pb[d]; also bf16 copy.
// ---------------------------------------------------------------------------
__global__ __launch_bounds__(256) void proj_kernel(const float* __restrict__ x,
                                                   const float* __restrict__ pw,
                                                   const float* __restrict__ pb,
                                                   float* __restrict__ h,
                                                   ushort_t* __restrict__ hbf) {
  int idx = blockIdx.x * 256 + threadIdx.x;        // ((b*L)+l)*512 + d
  int d = idx & 511;
  int l = (idx >> 9) & 1023;
  int b = idx >> 19;
  const float* xb = x + (size_t)b * 3 * 1024 + l;
  float v = pb[d] + xb[0] * pw[d * 3] + xb[1024] * pw[d * 3 + 1] + xb[2048] * pw[d * 3 + 2];
  h[idx] = v;
  hbf[idx] = f2bf(v);
}

// ---------------------------------------------------------------------------
// bf16 MFMA GEMM, global_load_lds + double-buffered prefetch.
// C[m,n] = act( sum_k A[m,k]*W[n,k] + bias[n] ).  Tile 128 x BN, BK=32.
// ACT: 0 none, 1 relu, 2 softplus. CBF: 1 bf16 C, 0 fp32 C.
// SPLITK: 1 direct; >1 -> partials at Cp + z*8192*ldc (no bias/act),
//   dtype of partials follows CBF (bf16 if CBF else fp32).
// ---------------------------------------------------------------------------
template <int ACT, int CBF, int SPLITK, int BN>
__global__ __launch_bounds__(256) void gemm_gll(const ushort_t* __restrict__ A,
                                                const ushort_t* __restrict__ W,
                                                const float* __restrict__ bias,
                                                void* __restrict__ Cp,
                                                int K, int lda, int ldc) {
  __shared__ ushort_t sA[2][4096];
  __shared__ ushort_t sB[2][BN * 32];
  constexpr int MREP = (BN == 128) ? 4 : 2;
  const int bm = blockIdx.y * 128, bn = blockIdx.x * BN;
  const int tid = threadIdx.x;
  const int wid = tid >> 6, lane = tid & 63;
  const int wrb = (BN == 128) ? (wid >> 1) * 64 : wid * 32;
  const int wcb = (BN == 128) ? (wid & 1) * 64 : 0;
  const int lr = lane & 15, ls = lane >> 4;
  const int sw = ls ^ ((lr >> 1) & 3);

  const int kseg = K / SPLITK;
  const int kbeg = (SPLITK > 1) ? blockIdx.z * kseg : 0;

  const int c0 = wid * 128 + lane;
  const int c1 = c0 + 64;
  const int r0 = c0 >> 2, s0 = (c0 & 3) ^ ((r0 >> 1) & 3);
  const int r1 = c1 >> 2, s1 = (c1 & 3) ^ ((r1 >> 1) & 3);
  const ushort_t* gA0 = A + (size_t)(bm + r0) * lda + kbeg + s0 * 8;
  const ushort_t* gA1 = A + (size_t)(bm + r1) * lda + kbeg + s1 * 8;
  const ushort_t* gB0;
  const ushort_t* gB1 = nullptr;
  if constexpr (BN == 128) {
    gB0 = W + (size_t)(bn + r0) * K + kbeg + s0 * 8;
    gB1 = W + (size_t)(bn + r1) * K + kbeg + s1 * 8;
  } else {
    const int cb = wid * 64 + lane;
    const int rb = cb >> 2, sb2 = (cb & 3) ^ ((rb >> 1) & 3);
    gB0 = W + (size_t)(bn + rb) * K + kbeg + sb2 * 8;
  }

  f32x4 acc[MREP][4];
#pragma unroll
  for (int i = 0; i < MREP; ++i)
#pragma unroll
    for (int j = 0; j < 4; ++j) acc[i][j] = (f32x4)(0.f);

#define STAGE(buf, step)                                             \
  do {                                                               \
    gll16(gA0 + (step) * 32, &sA[buf][wid * 1024]);                  \
    gll16(gA1 + (step) * 32, &sA[buf][wid * 1024 + 512]);            \
    if constexpr (BN == 128) {                                       \
      gll16(gB0 + (step) * 32, &sB[buf][wid * 1024]);                \
      gll16(gB1 + (step) * 32, &sB[buf][wid * 1024 + 512]);          \
    } else {                                                         \
      gll16(gB0 + (step) * 32, &sB[buf][wid * 512]);                 \
    }                                                                \
  } while (0)

  const int NT = kseg / 32;
  STAGE(0, 0);
  for (int t = 0; t < NT; ++t) {
    const int cur = t & 1;
    if (t + 1 < NT) {
      STAGE(cur ^ 1, t + 1);
      if constexpr (BN == 128)
        asm volatile("s_waitcnt vmcnt(4)" ::: "memory");
      else
        asm volatile("s_waitcnt vmcnt(3)" ::: "memory");
    } else {
      asm volatile("s_waitcnt vmcnt(0)" ::: "memory");
    }
    __builtin_amdgcn_sched_barrier(0);
    __builtin_amdgcn_s_barrier();
    __builtin_amdgcn_sched_barrier(0);

    bfrag af[MREP], bf[4];
#pragma unroll
    for (int mi = 0; mi < MREP; ++mi) {
      int row = wrb + mi * 16 + lr;
      af[mi] = *(const bfrag*)&sA[cur][(size_t)((row << 2) + sw) * 8];
    }
#pragma unroll
    for (int nj = 0; nj < 4; ++nj) {
      int col = wcb + nj * 16 + lr;
      bf[nj] = *(const bfrag*)&sB[cur][(size_t)((col << 2) + sw) * 8];
    }
#pragma unroll
    for (int mi = 0; mi < MREP; ++mi)
#pragma unroll
      for (int nj = 0; nj < 4; ++nj)
        acc[mi][nj] = __builtin_amdgcn_mfma_f32_16x16x32_bf16(af[mi], bf[nj], acc[mi][nj], 0, 0, 0);

    __builtin_amdgcn_s_barrier();
    __builtin_amdgcn_sched_barrier(0);
  }
#undef STAGE

  if (SPLITK > 1) {
#pragma unroll
    for (int nj = 0; nj < 4; ++nj) {
      int col = bn + wcb + nj * 16 + lr;
#pragma unroll
      for (int mi = 0; mi < MREP; ++mi) {
        int row0 = bm + wrb + mi * 16 + ls * 4;
#pragma unroll
        for (int r = 0; r < 4; ++r) {
          if (CBF)
            ((ushort_t*)Cp)[(size_t)blockIdx.z * 8192 * ldc +
                            (size_t)(row0 + r) * ldc + col] = f2bf(acc[mi][nj][r]);
          else
            ((float*)Cp)[(size_t)blockIdx.z * 8192 * ldc +
                         (size_t)(row0 + r) * ldc + col] = acc[mi][nj][r];
        }
      }
    }
  } else {
#pragma unroll
    for (int nj = 0; nj < 4; ++nj) {
      int col = bn + wcb + nj * 16 + lr;
      float bv = bias ? bias[col] : 0.f;
#pragma unroll
      for (int mi = 0; mi < MREP; ++mi) {
        int row0 = bm + wrb + mi * 16 + ls * 4;
#pragma unroll
        for (int r = 0; r < 4; ++r) {
          float v = acc[mi][nj][r] + bv;
          if (ACT == 1) v = fmaxf(v, 0.f);
          if (ACT == 2) v = (v > 20.f) ? v : log1pf(__expf(v));
          if (CBF)
            ((ushort_t*)Cp)[(size_t)(row0 + r) * ldc + col] = f2bf(v);
          else
            ((float*)Cp)[(size_t)(row0 + r) * ldc + col] = v;
        }
      }
    }
  }
}

// ---------------------------------------------------------------------------
// split-K=8 reduce for xproj: xdb fp32 + bf16 copy. 131072 float4 groups.
// ---------------------------------------------------------------------------
__global__ __launch_bounds__(256) void reduce8_xdb(const float* __restrict__ p,
                                                   float* __restrict__ xdb,
                                                   ushort_t* __restrict__ xdb_bf) {
  int i = blockIdx.x * 256 + threadIdx.x;
  float4 a = ((const float4*)p)[i];
#pragma unroll
  for (int z = 1; z < 8; ++z) {
    float4 b = ((const float4*)p)[i + z * 131072];
    a.x += b.x; a.y += b.y; a.z += b.z; a.w += b.w;
  }
  ((float4*)xdb)[i] = a;
  us4 o = {f2bf(a.x), f2bf(a.y), f2bf(a.z), f2bf(a.w)};
  ((us4*)xdb_bf)[i] = o;
}

// ---------------------------------------------------------------------------
// Depthwise causal conv (width 4) + SiLU, 2 channels/thread (u32 packed bf16).
// ---------------------------------------------------------------------------
__global__ __launch_bounds__(256) void conv_silu_kernel(const unsigned* __restrict__ xz,
                                                        const float* __restrict__ cw,
                                                        const float* __restrict__ cb,
                                                        unsigned* __restrict__ xc) {
  int idx = blockIdx.x * 256 + threadIdx.x;        // ((b*L)+t)*512 + dp
  int dp = idx & 511;
  int t = (idx >> 9) & 1023;
  int b = idx >> 19;
  int d0 = dp * 2;
  float a0 = cb[d0], a1 = cb[d0 + 1];
#pragma unroll
  for (int w = 0; w < 4; ++w) {
    int tt = t - 3 + w;
    if (tt >= 0) {
      unsigned v = xz[(((size_t)(b * 1024 + tt)) << 10) + dp];
      a0 += bf2f((ushort_t)(v & 0xffff)) * cw[d0 * 4 + w];
      a1 += bf2f((ushort_t)(v >> 16)) * cw[(d0 + 1) * 4 + w];
    }
  }
  unsigned o = (unsigned)f2bf(silu_f(a0)) | ((unsigned)f2bf(silu_f(a1)) << 16);
  xc[(((size_t)(b * 1024 + t)) << 9) + dp] = o;
}

// ---------------------------------------------------------------------------
// Chunked selective scan, STATE-SPLIT x4. xc, dt bf16.
// Pass1: P computed at chunk end as exp(A * sum(dt)) (1 add/iter, not 4 muls).
// ---------------------------------------------------------------------------
__global__ __launch_bounds__(256) void scan_pass1(const ushort_t* __restrict__ dt,
                                                  const float* __restrict__ xdb,
                                                  const ushort_t* __restrict__ xc,
                                                  const float* __restrict__ Alog,
                                                  float* __restrict__ scrP,
                                                  float* __restrict__ scrL) {
  int idx = blockIdx.x * 256 + threadIdx.x;
  int sh = idx & 3;
  int d = (idx >> 2) & 1023;
  int c = (idx >> 12) & 15;
  int b = idx >> 16;
  float A[4], st[4];
#pragma unroll
  for (int s = 0; s < 4; ++s) {
    A[s] = -__expf(Alog[d * 16 + sh * 4 + s]);
    st[s] = 0.f;
  }
  float dtsum = 0.f;
  int t0 = c * CLEN;
  size_t base = (((size_t)(b * 1024 + t0)) << 10) + d;
  const float* xb = xdb + (size_t)(b * 1024 + t0) * 64 + 32 + sh * 4;
  float dtv = bf2f(dt[base]), xv = bf2f(xc[base]);
  for (int t = 0; t < CLEN; ++t) {
    float dtn = 0.f, xvn = 0.f;
    if (t + 1 < CLEN) { dtn = bf2f(dt[base + 1024]); xvn = bf2f(xc[base + 1024]); }
    float4 Bv = *(const float4*)xb;
    float dx = dtv * xv;
    float e0 = __expf(dtv * A[0]), e1 = __expf(dtv * A[1]);
    float e2 = __expf(dtv * A[2]), e3 = __expf(dtv * A[3]);
    st[0] = st[0] * e0 + dx * Bv.x;
    st[1] = st[1] * e1 + dx * Bv.y;
    st[2] = st[2] * e2 + dx * Bv.z;
    st[3] = st[3] * e3 + dx * Bv.w;
    dtsum += dtv;
    base += 1024; xb += 64;
    dtv = dtn; xv = xvn;
  }
  size_t pbase = (((size_t)((b * 16 + c) * 16 + sh * 4)) << 10) + d;
#pragma unroll
  for (int s = 0; s < 4; ++s) {
    scrP[pbase + ((size_t)s << 10)] = __expf(A[s] * dtsum);
    scrL[pbase + ((size_t)s << 10)] = st[s];
  }
}

// ---------------------------------------------------------------------------
// Pass 2: combine chunks serially per (b,d,s).
// ---------------------------------------------------------------------------
__global__ __launch_bounds__(256) void scan_pass2(const float* __restrict__ scrP,
                                                  float* __restrict__ scrL) {
  int idx = blockIdx.x * 256 + threadIdx.x;        // ((b*16 + s)*1024 + d)
  int d = idx & 1023;
  int s = (idx >> 10) & 15;
  int b = idx >> 14;
  float cur = 0.f;
  for (int c = 0; c < 16; ++c) {
    size_t o = (((size_t)(((b * 16 + c) * 16) + s)) << 10) + d;
    float P = scrP[o];
    float loc = scrL[o];
    scrL[o] = cur;
    cur = cur * P + loc;
  }
}

// ---------------------------------------------------------------------------
// Pass 3: state-split x4 rescan; quad-reduce via shfl_xor; bf16 y out.
// ---------------------------------------------------------------------------
__global__ __launch_bounds__(256) void scan_pass3(const ushort_t* __restrict__ dt,
                                                  const float* __restrict__ xdb,
                                                  const ushort_t* __restrict__ xc,
                                                  const ushort_t* __restrict__ xz,
                                                  ushort_t* __restrict__ ybf,
                                                  const float* __restrict__ Alog,
                                                  const float* __restrict__ Dp,
                                                  const float* __restrict__ scrL) {
  int idx = blockIdx.x * 256 + threadIdx.x;
  int sh = idx & 3;
  int d = (idx >> 2) & 1023;
  int c = (idx >> 12) & 15;
  int b = idx >> 16;
  float A[4], st[4];
  size_t pbase = (((size_t)((b * 16 + c) * 16 + sh * 4)) << 10) + d;
#pragma unroll
  for (int s = 0; s < 4; ++s) {
    A[s] = -__expf(Alog[d * 16 + sh * 4 + s]);
    st[s] = scrL[pbase + ((size_t)s << 10)];
  }
  float Dv = Dp[d];
  int t0 = c * CLEN;
  size_t base = (((size_t)(b * 1024 + t0)) << 10) + d;
  size_t zoff = ((((size_t)(b * 1024 + t0)) << 11)) + 1024 + d;
  const float* xb = xdb + (size_t)(b * 1024 + t0) * 64 + 32 + sh * 4;
  float dtv = bf2f(dt[base]), xv = bf2f(xc[base]), zv = bf2f(xz[zoff]);
  for (int t = 0; t < CLEN; ++t) {
    float dtn = 0.f, xvn = 0.f, zvn = 0.f;
    if (t + 1 < CLEN) {
      dtn = bf2f(dt[base + 1024]); xvn = bf2f(xc[base + 1024]); zvn = bf2f(xz[zoff + 2048]);
    }
    float4 Bv = *(const float4*)xb;
    float4 Cv = *(const float4*)(xb + 16);
    float dx = dtv * xv;
    float e0 = __expf(dtv * A[0]), e1 = __expf(dtv * A[1]);
    float e2 = __expf(dtv * A[2]), e3 = __expf(dtv * A[3]);
    st[0] = st[0] * e0 + dx * Bv.x;
    st[1] = st[1] * e1 + dx * Bv.y;
    st[2] = st[2] * e2 + dx * Bv.z;
    st[3] = st[3] * e3 + dx * Bv.w;
    float acc = st[0] * Cv.x + st[1] * Cv.y + st[2] * Cv.z + st[3] * Cv.w;
    acc += __shfl_xor(acc, 1);
    acc += __shfl_xor(acc, 2);
    if (sh == 0)
      ybf[base] = f2bf((acc + Dv * xv) * silu_f(zv));
    base += 1024; zoff += 2048; xb += 64;
    dtv = dtn; xv = xvn; zv = zvn;
  }
}

// ---------------------------------------------------------------------------
// Residual + LayerNorm. add / out_bf may be nullptr.
// ---------------------------------------------------------------------------
__global__ __launch_bounds__(128) void resid_ln_kernel(const float* __restrict__ x,
                                                       const float* __restrict__ add,
                                                       const float* __restrict__ w,
                                                       const float* __restrict__ bias,
                                                       float* __restrict__ out,
                                                       ushort_t* __restrict__ out_bf) {
  int row = blockIdx.x, tid = threadIdx.x;
  float4 v = ((const float4*)(x + (size_t)row * 512))[tid];
  if (add) {
    float4 a = ((const float4*)(add + (size_t)row * 512))[tid];
    v.x += a.x; v.y += a.y; v.z += a.z; v.w += a.w;
  }
  float s = v.x + v.y + v.z + v.w;
  float ss = v.x * v.x + v.y * v.y + v.z * v.z + v.w * v.w;
#pragma unroll
  for (int o = 32; o; o >>= 1) {
    s += __shfl_xor(s, o);
    ss += __shfl_xor(ss, o);
  }
  __shared__ float red[4];
  int wid = tid >> 6;
  if ((tid & 63) == 0) { red[wid] = s; red[2 + wid] = ss; }
  __syncthreads();
  s = red[0] + red[1];
  ss = red[2] + red[3];
  float mean = s * (1.f / 512.f);
  float var = ss * (1.f / 512.f) - mean * mean;
  float inv = rsqrtf(var + 1e-5f);
  float4 wv = ((const float4*)w)[tid];
  float4 bv = ((const float4*)bias)[tid];
  float4 ov;
  ov.x = (v.x - mean) * inv * wv.x + bv.x;
  ov.y = (v.y - mean) * inv * wv.y + bv.y;
  ov.z = (v.z - mean) * inv * wv.z + bv.z;
  ov.w = (v.w - mean) * inv * wv.w + bv.w;
  ((float4*)(out + (size_t)row * 512))[tid] = ov;
  if (out_bf) {
    us4 ob = {f2bf(ov.x), f2bf(ov.y), f2bf(ov.z), f2bf(ov.w)};
    ((us4*)(out_bf + (size_t)row * 512))[tid] = ob;
  }
}

// ---------------------------------------------------------------------------
// Residual + split-K2 bf16 partial sum + optional gemm-bias + LayerNorm, fused.
// ---------------------------------------------------------------------------
__global__ __launch_bounds__(128) void resid_ln_sk(const float* __restrict__ x,
                                                   const ushort_t* __restrict__ p,
                                                   const float* __restrict__ pbias,
                                                   const float* __restrict__ w,
                                                   const float* __restrict__ bias,
                                                   float* __restrict__ out,
                                                   ushort_t* __restrict__ out_bf) {
  int row = blockIdx.x, tid = threadIdx.x;
  float4 v = ((const float4*)(x + (size_t)row * 512))[tid];
  us4 a = ((const us4*)(p + (size_t)row * 512))[tid];
  us4 c = ((const us4*)(p + 4194304 + (size_t)row * 512))[tid];
  v.x += bf2f(a.x) + bf2f(c.x);
  v.y += bf2f(a.y) + bf2f(c.y);
  v.z += bf2f(a.z) + bf2f(c.z);
  v.w += bf2f(a.w) + bf2f(c.w);
  if (pbias) {
    float4 pb = ((const float4*)pbias)[tid];
    v.x += pb.x; v.y += pb.y; v.z += pb.z; v.w += pb.w;
  }
  float s = v.x + v.y + v.z + v.w;
  float ss = v.x * v.x + v.y * v.y + v.z * v.z + v.w * v.w;
#pragma unroll
  for (int o = 32; o; o >>= 1) {
    s += __shfl_xor(s, o);
    ss += __shfl_xor(ss, o);
  }
  __shared__ float red[4];
  int wid = tid >> 6;
  if ((tid & 63) == 0) { red[wid] = s; red[2 + wid] = ss; }
  __syncthreads();
  s = red[0] + red[1];
  ss = red[2] + red[3];
  float mean = s * (1.f / 512.f);
  float var = ss * (1.f / 512.f) - mean * mean;
  float inv = rsqrtf(var + 1e-5f);
  float4 wv = ((const float4*)w)[tid];
  float4 bv = ((const float4*)bias)[tid];
  float4 ov;
  ov.x = (v.x - mean) * inv * wv.x + bv.x;
  ov.y = (v.y - mean) * inv * wv.y + bv.y;
  ov.z = (v.z - mean) * inv * wv.z + bv.z;
  ov.w = (v.w - mean) * inv * wv.w + bv.w;
  ((float4*)(out + (size_t)row * 512))[tid] = ov;
  us4 ob = {f2bf(ov.x), f2bf(ov.y), f2bf(ov.z), f2bf(ov.w)};
  ((us4*)(out_bf + (size_t)row * 512))[tid] = ob;
}

// ---------------------------------------------------------------------------
// Sinusoidal positional encoding add (in-place on h, refresh hbf)
// ---------------------------------------------------------------------------
__global__ __launch_bounds__(256) void posenc_kernel(float* __restrict__ h,
                                                     ushort_t* __restrict__ hbf) {
  int idx = blockIdx.x * 256 + threadIdx.x;
  int d = idx & 511;
  int l = (idx >> 9) & 1023;
  float freq = __expf(-(float)(d & ~1) * (9.210340371976184f / 512.f));
  float ang = (float)l * freq;
  float v = h[idx] + ((d & 1) ? cosf(ang) : sinf(ang));
  h[idx] = v;
  hbf[idx] = f2bf(v);
}

// ---------------------------------------------------------------------------
// MFMA flash attention v5: T14 async-stage split — K/V for tile t+1 loaded to
// registers while tile t computes; regs written to LDS after the free-barrier.
// XCD-aware decode; QBLK=64, grid 1024. bounds(256,5): LDS (32KB -> 5 blk/CU)
// is the occupancy limit, VGPR budget ~102 avoids spill.
// ---------------------------------------------------------------------------
__global__ __launch_bounds__(256, 5) void attn_mfma(const ushort_t* __restrict__ qkv,
                                                    ushort_t* __restrict__ ao) {
  __shared__ unsigned short Qs[4096];
  __shared__ unsigned short Ks[4096];
  __shared__ unsigned short Vt[4096];
  __shared__ unsigned short Ps[4096];
  const int tid = threadIdx.x;
  const int w = blockIdx.x;                      // 1024 blocks
  const int bh = (w & 7) + (w >> 7) * 8;         // b*8 + h (XCD w%8 keeps bh)
  const int qt = (w >> 3) & 15;
  const int hh = bh & 7, b = bh >> 3;
  const int l0 = qt * 64;
  const size_t bb = (size_t)b * 1024 * 1536;

  const int srow = tid >> 2;
  const int sdb = (tid & 3) << 4;
  const int sc0 = sdb >> 3;

  {
    const ushort_t* qp = qkv + bb + (size_t)(l0 + srow) * 1536 + hh * 64 + sdb;
    *(bfrag*)&Qs[srow * 64 + ((sc0 ^ (srow & 7)) << 3)] = *(const bfrag*)qp;
    *(bfrag*)&Qs[srow * 64 + (((sc0 + 1) ^ (srow & 7)) << 3)] = *(const bfrag*)(qp + 8);
  }

  union B8 { bfrag v; ushort_t u[8]; };
  bfrag k0, k1;
  B8 v0, v1;
  {
    const ushort_t* kp = qkv + bb + (size_t)srow * 1536 + hh * 64 + 512 + sdb;
    k0 = *(const bfrag*)kp;
    k1 = *(const bfrag*)(kp + 8);
    v0.v = *(const bfrag*)(kp + 512);
    v1.v = *(const bfrag*)(kp + 520);
  }

  const int wid = tid >> 6, lane = tid & 63;
  const int l15 = lane & 15, rg = lane >> 4;
  const int l7 = l15 & 7;
  float m[4], lsum[4];
  f32x4 oacc[4];
#pragma unroll
  for (int r = 0; r < 4; ++r) { m[r] = -1e30f; lsum[r] = 0.f; }
#pragma unroll
  for (int nt = 0; nt < 4; ++nt) oacc[nt] = (f32x4)(0.f);

  for (int jt = 0; jt < 16; ++jt) {
    __syncthreads();   // all waves done reading LDS from previous tile
    // write current tile's K (vector) and V (transposed scalar) to LDS
    *(bfrag*)&Ks[srow * 64 + ((sc0 ^ (srow & 7)) << 3)] = k0;
    *(bfrag*)&Ks[srow * 64 + (((sc0 + 1) ^ (srow & 7)) << 3)] = k1;
#pragma unroll
    for (int j = 0; j < 16; ++j) {
      int dd = sdb + j;
      ushort_t val = (j < 8) ? v0.u[j] : v1.u[j - 8];
      Vt[dd * 64 + (((srow >> 3) ^ (dd & 7) ^ ((dd >> 3) & 7)) << 3) + (srow & 7)] = val;
    }
    // issue next tile's loads; latency hides under this tile's compute
    if (jt + 1 < 16) {
      const ushort_t* kp = qkv + bb + (size_t)((jt + 1) * 64 + srow) * 1536 + hh * 64 + 512 + sdb;
      k0 = *(const bfrag*)kp;
      k1 = *(const bfrag*)(kp + 8);
      v0.v = *(const bfrag*)(kp + 512);
      v1.v = *(const bfrag*)(kp + 520);
    }
    __syncthreads();   // LDS tile ready

    bfrag aq[2];
#pragma unroll
    for (int ks = 0; ks < 2; ++ks)
      aq[ks] = *(const bfrag*)&Qs[(wid * 16 + l15) * 64 + (((ks * 4 + rg) ^ l7) << 3)];
    f32x4 sc[4];
#pragma unroll
    for (int nt = 0; nt < 4; ++nt) {
      f32x4 s = (f32x4)(0.f);
#pragma unroll
      for (int ks = 0; ks < 2; ++ks) {
        bfrag bk = *(const bfrag*)&Ks[(nt * 16 + l15) * 64 + (((ks * 4 + rg) ^ l7) << 3)];
        s = __builtin_amdgcn_mfma_f32_16x16x32_bf16(aq[ks], bk, s, 0, 0, 0);
      }
      sc[nt] = s * 0.125f;
    }

#pragma unroll
    for (int r = 0; r < 4; ++r) {
      float mc = fmaxf(fmaxf(sc[0][r], sc[1][r]), fmaxf(sc[2][r], sc[3][r]));
#pragma unroll
      for (int o = 8; o; o >>= 1) mc = fmaxf(mc, __shfl_xor(mc, o));
      float mn = fmaxf(m[r], mc);
      float al = __expf(m[r] - mn);
      m[r] = mn;
      int prow = rg * 4 + r;
      float ps = 0.f;
#pragma unroll
      for (int nt = 0; nt < 4; ++nt) {
        float p = __expf(sc[nt][r] - mn);
        ps += p;
        int col = nt * 16 + l15;
        Ps[wid * 1024 + prow * 64 + ((((col >> 3) ^ (prow & 7))) << 3) + (col & 7)] =
            (ushort_t)(__float_as_uint(p) >> 16);   // truncating bf16
      }
#pragma unroll
      for (int o = 8; o; o >>= 1) ps += __shfl_xor(ps, o);
      lsum[r] = lsum[r] * al + ps;
#pragma unroll
      for (int nt = 0; nt < 4; ++nt) oacc[nt][r] *= al;
    }

    bfrag ap[2];
#pragma unroll
    for (int ks = 0; ks < 2; ++ks)
      ap[ks] = *(const bfrag*)&Ps[wid * 1024 + l15 * 64 + (((ks * 4 + rg) ^ l7) << 3)];
#pragma unroll
    for (int nt = 0; nt < 4; ++nt) {
      int vrow = nt * 16 + l15;
#pragma unroll
      for (int ks = 0; ks < 2; ++ks) {
        bfrag bv = *(const bfrag*)&Vt[vrow * 64 +
            (((ks * 4 + rg) ^ (vrow & 7) ^ ((vrow >> 3) & 7)) << 3)];
        oacc[nt] = __builtin_amdgcn_mfma_f32_16x16x32_bf16(ap[ks], bv, oacc[nt], 0, 0, 0);
      }
    }
  }

#pragma unroll
  for (int r = 0; r < 4; ++r) {
    float inv = 1.f / lsum[r];
    int row = l0 + wid * 16 + rg * 4 + r;
    ushort_t* op = ao + ((size_t)(b * 1024 + row)) * 512 + hh * 64;
#pragma unroll
    for (int nt = 0; nt < 4; ++nt) op[nt * 16 + l15] = f2bf(oacc[nt][r] * inv);
  }
}

// ---------------------------------------------------------------------------
// Mean over L, two-pass.
// ---------------------------------------------------------------------------
__global__ __launch_bounds__(512) void mean_part(const float* __restrict__ h,
                                                 float* __restrict__ part) {
  int blk = blockIdx.x;                       // b*16 + lc
  int b = blk >> 4, lc = blk & 15, d = threadIdx.x;
  float s = 0.f;
  int l0 = lc * 64;
  for (int l = l0; l < l0 + 64; ++l) s += h[(((size_t)(b * 1024 + l)) << 9) + d];
  part[((size_t)blk << 9) + d] = s;
}
__global__ __launch_bounds__(256) void mean_final(const float* __restrict__ part,
                                                  float* __restrict__ out2) {
  int i = blockIdx.x * 256 + threadIdx.x;     // b*512 + d
  int b = i >> 9, d = i & 511;
  float s = 0.f;
#pragma unroll
  for (int c = 0; c < 16; ++c) s += part[(((size_t)(b * 16 + c)) << 9) + d];
  out2[i] = s * (1.f / 1024.f);
}

// ---------------------------------------------------------------------------
extern "C" void kernel_launch(void* const* d_in, const int* in_sizes, int n_in,
                              void* d_out, int out_size, void* d_ws, size_t ws_size,
                              hipStream_t stream) {
  const float* x        = (const float*)d_in[0];
  const float* proj_w   = (const float*)d_in[1];
  const float* proj_b   = (const float*)d_in[2];
  const float* m_in_w   = (const float*)d_in[3];
  const float* m_conv_w = (const float*)d_in[4];
  const float* m_conv_b = (const float*)d_in[5];
  const float* m_xproj_w= (const float*)d_in[6];
  const float* m_dt_w   = (const float*)d_in[7];
  const float* m_dt_b   = (const float*)d_in[8];
  const float* m_Alog   = (const float*)d_in[9];
  const float* m_D      = (const float*)d_in[10];
  const float* m_out_w  = (const float*)d_in[11];
  const float* m_ln_w   = (const float*)d_in[12];
  const float* m_ln_b   = (const float*)d_in[13];
  const float* t_qkv_w  = (const float*)d_in[14];
  const float* t_qkv_b  = (const float*)d_in[15];
  const float* t_ow     = (const float*)d_in[16];
  const float* t_ob     = (const float*)d_in[17];
  const float* t_l1w    = (const float*)d_in[18];
  const float* t_l1b    = (const float*)d_in[19];
  const float* t_l2w    = (const float*)d_in[20];
  const float* t_l2b    = (const float*)d_in[21];
  const float* t_ln1w   = (const float*)d_in[22];
  const float* t_ln1b   = (const float*)d_in[23];
  const float* t_ln2w   = (const float*)d_in[24];
  const float* t_ln2b   = (const float*)d_in[25];
  const float* no_w     = (const float*)d_in[26];
  const float* no_b     = (const float*)d_in[27];

  float* ws   = (float*)d_ws;
  float* h    = ws;                                   //  4M f
  ushort_t* h_bf = (ushort_t*)(ws + 4194304);         //  4M us (2M f)
  float* bufA = ws + 6291456;                         // 16M f (xz_bf / qkv_bf / ff1_bf)
  float* bufB = bufA + 16777216;                      //  8M f (xc_bf / ao_bf)
  float* bufC = bufB + 8388608;                       //  8M f (xproj partials / dt_bf / split-K partials)
  float* bufE = bufC + 8388608;                       //  4M f (scan scratch)
  float* bufF = bufE + 4194304;                       //  0.5M f (xdb f32 / mean partials)
  ushort_t* y_bf = (ushort_t*)(bufF + 524288);        //  8M us (4M f)
  ushort_t* wbf  = (ushort_t*)(bufF + 524288 + 4194304);
  float* scrP = bufE;
  float* scrL = bufE + 2097152;

  // bf16 weight pool offsets (ushort units)
  ushort_t* wIN  = wbf;                 // 2 x 2048 x 512   = 2,097,152
  ushort_t* wOUT = wbf + 2097152;       // 2 x 512 x 1024   = 1,048,576
  ushort_t* wQKV = wbf + 3145728;       // 2 x 1536 x 512   = 1,572,864
  ushort_t* wOW  = wbf + 4718592;       // 2 x 512 x 512    =   524,288
  ushort_t* wL1  = wbf + 5242880;       // 2 x 2048 x 512   = 2,097,152
  ushort_t* wL2  = wbf + 7340032;       // 2 x 512 x 2048   = 2,097,152
  ushort_t* wXP  = wbf + 9437184;       // 2 x 64 x 1024    =   131,072
  ushort_t* wDT  = wbf + 9568256;       // 2 x 1024 x 32    =    65,536
  ushort_t* xdb_bf = wbf + 9633792;     // 8192 x 64        =   524,288

  Cvt8Args ca;
  ca.s[0] = m_in_w;    ca.d[0] = wIN;
  ca.s[1] = m_out_w;   ca.d[1] = wOUT;
  ca.s[2] = t_qkv_w;   ca.d[2] = wQKV;
  ca.s[3] = t_ow;      ca.d[3] = wOW;
  ca.s[4] = t_l1w;     ca.d[4] = wL1;
  ca.s[5] = t_l2w;     ca.d[5] = wL2;
  ca.s[6] = m_xproj_w; ca.d[6] = wXP;
  ca.s[7] = m_dt_w;    ca.d[7] = wDT;
  ca.end[0] = 2048; ca.end[1] = 3072; ca.end[2] = 4608; ca.end[3] = 5120;
  ca.end[4] = 7168; ca.end[5] = 9216; ca.end[6] = 9344; ca.end[7] = 9408;
  cvt8<<<9408, 256, 0, stream>>>(ca);

  proj_kernel<<<16384, 256, 0, stream>>>(x, proj_w, proj_b, h, h_bf);

  for (int i = 0; i < 2; ++i) {
    // xz = h @ in_w^T   (8192 x 2048, K=512) -> bf16
    gemm_gll<0, 1, 1, 128><<<dim3(16, 64), 256, 0, stream>>>(
        h_bf, wIN + (size_t)i * 1048576, nullptr, bufA, DMODEL, DMODEL, 2 * DINNER);
    // xc = silu(causal_conv(xm)) -> bf16 (2 ch/thread)
    conv_silu_kernel<<<16384, 256, 0, stream>>>((const unsigned*)bufA,
                                                m_conv_w + i * DINNER * 4,
                                                m_conv_b + i * DINNER, (unsigned*)bufB);
    // xdb = xc @ xp_w^T  (8192 x 64, K=1024), MFMA split-K=8 (fp32 partials)
    gemm_gll<0, 0, 8, 64><<<dim3(1, 64, 8), 256, 0, stream>>>(
        (const ushort_t*)bufB, wXP + (size_t)i * 65536, nullptr, bufC,
        DINNER, DINNER, 64);
    reduce8_xdb<<<512, 256, 0, stream>>>(bufC, bufF, xdb_bf);
    // dt = softplus(xdb[:, :32] @ dt_w^T + dt_b), MFMA K=32 -> bufC bf16
    gemm_gll<2, 1, 1, 128><<<dim3(8, 64), 256, 0, stream>>>(
        xdb_bf, wDT + (size_t)i * 32768, m_dt_b + i * DINNER, bufC,
        DTRANK, 64, DINNER);
    // chunked selective scan (state-split x4) -> y_bf (bf16)
    scan_pass1<<<2048, 256, 0, stream>>>((const ushort_t*)bufC, bufF, (const ushort_t*)bufB,
                                         m_Alog + (size_t)i * DINNER * DSTATE, scrP, scrL);
    scan_pass2<<<512, 256, 0, stream>>>(scrP, scrL);
    scan_pass3<<<2048, 256, 0, stream>>>((const ushort_t*)bufC, bufF, (const ushort_t*)bufB,
                                         (const ushort_t*)bufA, y_bf,
                                         m_Alog + (size_t)i * DINNER * DSTATE,
                                         m_D + i * DINNER, scrL);
    // mamba_out = y @ out_w^T  (8192 x 512, K=1024), split-K=2 bf16 partials
    gemm_gll<0, 1, 2, 128><<<dim3(4, 64, 2), 256, 0, stream>>>(
        y_bf, wOUT + (size_t)i * 524288, nullptr, bufC, DINNER, DINNER, DMODEL);
    resid_ln_sk<<<8192, 128, 0, stream>>>(h, (const ushort_t*)bufC, nullptr,
                                          m_ln_w + i * DMODEL, m_ln_b + i * DMODEL, h, h_bf);
  }

  posenc_kernel<<<16384, 256, 0, stream>>>(h, h_bf);

  for (int i = 0; i < 2; ++i) {
    // qkv = h @ qkv_w^T + qkv_b  (8192 x 1536, K=512) -> bf16
    gemm_gll<0, 1, 1, 128><<<dim3(12, 64), 256, 0, stream>>>(
        h_bf, wQKV + (size_t)i * 786432, t_qkv_b + i * 3 * DMODEL, bufA,
        DMODEL, DMODEL, 3 * DMODEL);
    // MFMA flash attention (XCD-swizzled, pipelined staging) -> ao bf16
    attn_mfma<<<1024, 256, 0, stream>>>((const ushort_t*)bufA, (ushort_t*)bufB);
    // attn_proj = ao @ ow^T  (8192 x 512, K=512), split-K=2 bf16 partials
    gemm_gll<0, 1, 2, 128><<<dim3(4, 64, 2), 256, 0, stream>>>(
        (const ushort_t*)bufB, wOW + (size_t)i * 262144, nullptr, bufC,
        DMODEL, DMODEL, DMODEL);
    resid_ln_sk<<<8192, 128, 0, stream>>>(h, (const ushort_t*)bufC, t_ob + i * DMODEL,
                                          t_ln1w + i * DMODEL, t_ln1b + i * DMODEL, h, h_bf);
    // ff1 = relu(h @ l1w^T + l1b)  (8192 x 2048, K=512) -> bf16
    gemm_gll<1, 1, 1, 128><<<dim3(16, 64), 256, 0, stream>>>(
        h_bf, wL1 + (size_t)i * 1048576, t_l1b + i * DFF, bufA,
        DMODEL, DMODEL, DFF);
    // ff2 = ff1 @ l2w^T  (8192 x 512, K=2048), split-K=2 bf16 partials
    gemm_gll<0, 1, 2, 128><<<dim3(4, 64, 2), 256, 0, stream>>>(
        (const ushort_t*)bufA, wL2 + (size_t)i * 1048576, nullptr, bufC,
        DFF, DFF, DMODEL);
    resid_ln_sk<<<8192, 128, 0, stream>>>(h, (const ushort_t*)bufC, t_l2b + i * DMODEL,
                                          t_ln2w + i * DMODEL, t_ln2b + i * DMODEL, h, h_bf);
  }

  // final LN -> d_out, then mean over L -> d_out tail
  float* out_h = (float*)d_out;
  resid_ln_kernel<<<8192, 128, 0, stream>>>(h, nullptr, no_w, no_b, out_h, nullptr);
  mean_part<<<128, 512, 0, stream>>>(out_h, bufF);
  mean_final<<<16, 256, 0, stream>>>(bufF, out_h + 4194304);
}

// Round 14
// 942.704 us; speedup vs baseline: 1.2051x; 1.2051x over previous
//
#include <hip/hip_runtime.h>
#include <cstddef>

// Problem constants
#define BATCH 8
#define LSEQ 1024
#define DMODEL 512
#define DINNER 1024
#define DSTATE 16
#define DTRANK 32
#define NHEAD 8
#define DHEAD 64
#define DFF 2048
#define MTOK 8192   // BATCH*LSEQ
#define NCHUNK 16
#define CLEN 64     // LSEQ / NCHUNK

typedef __attribute__((ext_vector_type(8))) short bfrag;          // 8 bf16 = 16 B
typedef __attribute__((ext_vector_type(4))) float f32x4;          // MFMA acc
typedef __attribute__((ext_vector_type(4))) unsigned short us4;
typedef unsigned short ushort_t;

__device__ __forceinline__ float silu_f(float x) { return x / (1.f + __expf(-x)); }

__device__ __forceinline__ unsigned short f2bf(float f) {  // RNE fp32->bf16
  unsigned u = __float_as_uint(f);
  return (unsigned short)((u + 0x7FFFu + ((u >> 16) & 1u)) >> 16);
}
__device__ __forceinline__ float bf2f(ushort_t u) {
  return __uint_as_float((unsigned)u << 16);
}

// async global->LDS, 16B per lane. LDS dest = wave-uniform base + lane*16.
__device__ __forceinline__ void gll16(const ushort_t* g, ushort_t* l) {
  __builtin_amdgcn_global_load_lds(
      (const __attribute__((address_space(1))) unsigned int*)g,
      (__attribute__((address_space(3))) unsigned int*)l, 16, 0, 0);
}

// ---------------------------------------------------------------------------
// 8-segment fp32 -> bf16 weight convert (single launch).
// ---------------------------------------------------------------------------
struct Cvt8Args {
  const float* s[8];
  ushort_t* d[8];
  int end[8];   // prefix-sum of blocks
};
__global__ __launch_bounds__(256) void cvt8(Cvt8Args a) {
  int blk = blockIdx.x;
  int seg = 0, start = 0;
#pragma unroll
  for (int i = 0; i < 7; ++i)
    if (blk >= a.end[i]) { seg = i + 1; start = a.end[i]; }
  int i4 = (blk - start) * 256 + threadIdx.x;
  float4 v = ((const float4*)a.s[seg])[i4];
  us4 o = {f2bf(v.x), f2bf(v.y), f2bf(v.z), f2bf(v.w)};
  ((us4*)a.d[seg])[i4] = o;
}

// ---------------------------------------------------------------------------
// Input projection: h[b,l,d] = sum_c x[b,c,l] * pw[d,c] + pb[d]; also bf16 copy.
// ---------------------------------------------------------------------------
__global__ __launch_bounds__(256) void proj_kernel(const float* __restrict__ x,
                                                   const float* __restrict__ pw,
                                                   const float* __restrict__ pb,
                                                   float* __restrict__ h,
                                                   ushort_t* __restrict__ hbf) {
  int idx = blockIdx.x * 256 + threadIdx.x;        // ((b*L)+l)*512 + d
  int d = idx & 511;
  int l = (idx >> 9) & 1023;
  int b = idx >> 19;
  const float* xb = x + (size_t)b * 3 * 1024 + l;
  float v = pb[d] + xb[0] * pw[d * 3] + xb[1024] * pw[d * 3 + 1] + xb[2048] * pw[d * 3 + 2];
  h[idx] = v;
  hbf[idx] = f2bf(v);
}

// ---------------------------------------------------------------------------
// bf16 MFMA GEMM, global_load_lds + double-buffered prefetch.
// C[m,n] = act( sum_k A[m,k]*W[n,k] + bias[n] ).  Tile 128 x BN, BK=32.
// ACT: 0 none, 1 relu, 2 softplus. CBF: 1 bf16 C, 0 fp32 C.
// SPLITK: 1 direct; >1 -> partials at Cp + z*8192*ldc (no bias/act),
//   dtype of partials follows CBF (bf16 if CBF else fp32).
// ---------------------------------------------------------------------------
template <int ACT, int CBF, int SPLITK, int BN>
__global__ __launch_bounds__(256) void gemm_gll(const ushort_t* __restrict__ A,
                                                const ushort_t* __restrict__ W,
                                                const float* __restrict__ bias,
                                                void* __restrict__ Cp,
                                                int K, int lda, int ldc) {
  __shared__ ushort_t sA[2][4096];
  __shared__ ushort_t sB[2][BN * 32];
  constexpr int MREP = (BN == 128) ? 4 : 2;
  const int bm = blockIdx.y * 128, bn = blockIdx.x * BN;
  const int tid = threadIdx.x;
  const int wid = tid >> 6, lane = tid & 63;
  const int wrb = (BN == 128) ? (wid >> 1) * 64 : wid * 32;
  const int wcb = (BN == 128) ? (wid & 1) * 64 : 0;
  const int lr = lane & 15, ls = lane >> 4;
  const int sw = ls ^ ((lr >> 1) & 3);

  const int kseg = K / SPLITK;
  const int kbeg = (SPLITK > 1) ? blockIdx.z * kseg : 0;

  const int c0 = wid * 128 + lane;
  const int c1 = c0 + 64;
  const int r0 = c0 >> 2, s0 = (c0 & 3) ^ ((r0 >> 1) & 3);
  const int r1 = c1 >> 2, s1 = (c1 & 3) ^ ((r1 >> 1) & 3);
  const ushort_t* gA0 = A + (size_t)(bm + r0) * lda + kbeg + s0 * 8;
  const ushort_t* gA1 = A + (size_t)(bm + r1) * lda + kbeg + s1 * 8;
  const ushort_t* gB0;
  const ushort_t* gB1 = nullptr;
  if constexpr (BN == 128) {
    gB0 = W + (size_t)(bn + r0) * K + kbeg + s0 * 8;
    gB1 = W + (size_t)(bn + r1) * K + kbeg + s1 * 8;
  } else {
    const int cb = wid * 64 + lane;
    const int rb = cb >> 2, sb2 = (cb & 3) ^ ((rb >> 1) & 3);
    gB0 = W + (size_t)(bn + rb) * K + kbeg + sb2 * 8;
  }

  f32x4 acc[MREP][4];
#pragma unroll
  for (int i = 0; i < MREP; ++i)
#pragma unroll
    for (int j = 0; j < 4; ++j) acc[i][j] = (f32x4)(0.f);

#define STAGE(buf, step)                                             \
  do {                                                               \
    gll16(gA0 + (step) * 32, &sA[buf][wid * 1024]);                  \
    gll16(gA1 + (step) * 32, &sA[buf][wid * 1024 + 512]);            \
    if constexpr (BN == 128) {                                       \
      gll16(gB0 + (step) * 32, &sB[buf][wid * 1024]);                \
      gll16(gB1 + (step) * 32, &sB[buf][wid * 1024 + 512]);          \
    } else {                                                         \
      gll16(gB0 + (step) * 32, &sB[buf][wid * 512]);                 \
    }                                                                \
  } while (0)

  const int NT = kseg / 32;
  STAGE(0, 0);
  for (int t = 0; t < NT; ++t) {
    const int cur = t & 1;
    if (t + 1 < NT) {
      STAGE(cur ^ 1, t + 1);
      if constexpr (BN == 128)
        asm volatile("s_waitcnt vmcnt(4)" ::: "memory");
      else
        asm volatile("s_waitcnt vmcnt(3)" ::: "memory");
    } else {
      asm volatile("s_waitcnt vmcnt(0)" ::: "memory");
    }
    __builtin_amdgcn_sched_barrier(0);
    __builtin_amdgcn_s_barrier();
    __builtin_amdgcn_sched_barrier(0);

    bfrag af[MREP], bf[4];
#pragma unroll
    for (int mi = 0; mi < MREP; ++mi) {
      int row = wrb + mi * 16 + lr;
      af[mi] = *(const bfrag*)&sA[cur][(size_t)((row << 2) + sw) * 8];
    }
#pragma unroll
    for (int nj = 0; nj < 4; ++nj) {
      int col = wcb + nj * 16 + lr;
      bf[nj] = *(const bfrag*)&sB[cur][(size_t)((col << 2) + sw) * 8];
    }
#pragma unroll
    for (int mi = 0; mi < MREP; ++mi)
#pragma unroll
      for (int nj = 0; nj < 4; ++nj)
        acc[mi][nj] = __builtin_amdgcn_mfma_f32_16x16x32_bf16(af[mi], bf[nj], acc[mi][nj], 0, 0, 0);

    __builtin_amdgcn_s_barrier();
    __builtin_amdgcn_sched_barrier(0);
  }
#undef STAGE

  if (SPLITK > 1) {
#pragma unroll
    for (int nj = 0; nj < 4; ++nj) {
      int col = bn + wcb + nj * 16 + lr;
#pragma unroll
      for (int mi = 0; mi < MREP; ++mi) {
        int row0 = bm + wrb + mi * 16 + ls * 4;
#pragma unroll
        for (int r = 0; r < 4; ++r) {
          if (CBF)
            ((ushort_t*)Cp)[(size_t)blockIdx.z * 8192 * ldc +
                            (size_t)(row0 + r) * ldc + col] = f2bf(acc[mi][nj][r]);
          else
            ((float*)Cp)[(size_t)blockIdx.z * 8192 * ldc +
                         (size_t)(row0 + r) * ldc + col] = acc[mi][nj][r];
        }
      }
    }
  } else {
#pragma unroll
    for (int nj = 0; nj < 4; ++nj) {
      int col = bn + wcb + nj * 16 + lr;
      float bv = bias ? bias[col] : 0.f;
#pragma unroll
      for (int mi = 0; mi < MREP; ++mi) {
        int row0 = bm + wrb + mi * 16 + ls * 4;
#pragma unroll
        for (int r = 0; r < 4; ++r) {
          float v = acc[mi][nj][r] + bv;
          if (ACT == 1) v = fmaxf(v, 0.f);
          if (ACT == 2) v = (v > 20.f) ? v : log1pf(__expf(v));
          if (CBF)
            ((ushort_t*)Cp)[(size_t)(row0 + r) * ldc + col] = f2bf(v);
          else
            ((float*)Cp)[(size_t)(row0 + r) * ldc + col] = v;
        }
      }
    }
  }
}

// ---------------------------------------------------------------------------
// split-K=8 reduce for xproj: xdb fp32 + bf16 copy. 131072 float4 groups.
// ---------------------------------------------------------------------------
__global__ __launch_bounds__(256) void reduce8_xdb(const float* __restrict__ p,
                                                   float* __restrict__ xdb,
                                                   ushort_t* __restrict__ xdb_bf) {
  int i = blockIdx.x * 256 + threadIdx.x;
  float4 a = ((const float4*)p)[i];
#pragma unroll
  for (int z = 1; z < 8; ++z) {
    float4 b = ((const float4*)p)[i + z * 131072];
    a.x += b.x; a.y += b.y; a.z += b.z; a.w += b.w;
  }
  ((float4*)xdb)[i] = a;
  us4 o = {f2bf(a.x), f2bf(a.y), f2bf(a.z), f2bf(a.w)};
  ((us4*)xdb_bf)[i] = o;
}

// ---------------------------------------------------------------------------
// Depthwise causal conv (width 4) + SiLU, 2 channels/thread (u32 packed bf16).
// ---------------------------------------------------------------------------
__global__ __launch_bounds__(256) void conv_silu_kernel(const unsigned* __restrict__ xz,
                                                        const float* __restrict__ cw,
                                                        const float* __restrict__ cb,
                                                        unsigned* __restrict__ xc) {
  int idx = blockIdx.x * 256 + threadIdx.x;        // ((b*L)+t)*512 + dp
  int dp = idx & 511;
  int t = (idx >> 9) & 1023;
  int b = idx >> 19;
  int d0 = dp * 2;
  float a0 = cb[d0], a1 = cb[d0 + 1];
#pragma unroll
  for (int w = 0; w < 4; ++w) {
    int tt = t - 3 + w;
    if (tt >= 0) {
      unsigned v = xz[(((size_t)(b * 1024 + tt)) << 10) + dp];
      a0 += bf2f((ushort_t)(v & 0xffff)) * cw[d0 * 4 + w];
      a1 += bf2f((ushort_t)(v >> 16)) * cw[(d0 + 1) * 4 + w];
    }
  }
  unsigned o = (unsigned)f2bf(silu_f(a0)) | ((unsigned)f2bf(silu_f(a1)) << 16);
  xc[(((size_t)(b * 1024 + t)) << 9) + dp] = o;
}

// ---------------------------------------------------------------------------
// Chunked selective scan, STATE-SPLIT x4. xc, dt bf16.
// Pass1: P computed at chunk end as exp(A * sum(dt)).
// ---------------------------------------------------------------------------
__global__ __launch_bounds__(256) void scan_pass1(const ushort_t* __restrict__ dt,
                                                  const float* __restrict__ xdb,
                                                  const ushort_t* __restrict__ xc,
                                                  const float* __restrict__ Alog,
                                                  float* __restrict__ scrP,
                                                  float* __restrict__ scrL) {
  int idx = blockIdx.x * 256 + threadIdx.x;
  int sh = idx & 3;
  int d = (idx >> 2) & 1023;
  int c = (idx >> 12) & 15;
  int b = idx >> 16;
  float A[4], st[4];
#pragma unroll
  for (int s = 0; s < 4; ++s) {
    A[s] = -__expf(Alog[d * 16 + sh * 4 + s]);
    st[s] = 0.f;
  }
  float dtsum = 0.f;
  int t0 = c * CLEN;
  size_t base = (((size_t)(b * 1024 + t0)) << 10) + d;
  const float* xb = xdb + (size_t)(b * 1024 + t0) * 64 + 32 + sh * 4;
  float dtv = bf2f(dt[base]), xv = bf2f(xc[base]);
  for (int t = 0; t < CLEN; ++t) {
    float dtn = 0.f, xvn = 0.f;
    if (t + 1 < CLEN) { dtn = bf2f(dt[base + 1024]); xvn = bf2f(xc[base + 1024]); }
    float4 Bv = *(const float4*)xb;
    float dx = dtv * xv;
    float e0 = __expf(dtv * A[0]), e1 = __expf(dtv * A[1]);
    float e2 = __expf(dtv * A[2]), e3 = __expf(dtv * A[3]);
    st[0] = st[0] * e0 + dx * Bv.x;
    st[1] = st[1] * e1 + dx * Bv.y;
    st[2] = st[2] * e2 + dx * Bv.z;
    st[3] = st[3] * e3 + dx * Bv.w;
    dtsum += dtv;
    base += 1024; xb += 64;
    dtv = dtn; xv = xvn;
  }
  size_t pbase = (((size_t)((b * 16 + c) * 16 + sh * 4)) << 10) + d;
#pragma unroll
  for (int s = 0; s < 4; ++s) {
    scrP[pbase + ((size_t)s << 10)] = __expf(A[s] * dtsum);
    scrL[pbase + ((size_t)s << 10)] = st[s];
  }
}

// ---------------------------------------------------------------------------
// Pass 2: combine chunks serially per (b,d,s).
// ---------------------------------------------------------------------------
__global__ __launch_bounds__(256) void scan_pass2(const float* __restrict__ scrP,
                                                  float* __restrict__ scrL) {
  int idx = blockIdx.x * 256 + threadIdx.x;        // ((b*16 + s)*1024 + d)
  int d = idx & 1023;
  int s = (idx >> 10) & 15;
  int b = idx >> 14;
  float cur = 0.f;
  for (int c = 0; c < 16; ++c) {
    size_t o = (((size_t)(((b * 16 + c) * 16) + s)) << 10) + d;
    float P = scrP[o];
    float loc = scrL[o];
    scrL[o] = cur;
    cur = cur * P + loc;
  }
}

// ---------------------------------------------------------------------------
// Pass 3: state-split x4 rescan; quad-reduce via shfl_xor; bf16 y out.
// ---------------------------------------------------------------------------
__global__ __launch_bounds__(256) void scan_pass3(const ushort_t* __restrict__ dt,
                                                  const float* __restrict__ xdb,
                                                  const ushort_t* __restrict__ xc,
                                                  const ushort_t* __restrict__ xz,
                                                  ushort_t* __restrict__ ybf,
                                                  const float* __restrict__ Alog,
                                                  const float* __restrict__ Dp,
                                                  const float* __restrict__ scrL) {
  int idx = blockIdx.x * 256 + threadIdx.x;
  int sh = idx & 3;
  int d = (idx >> 2) & 1023;
  int c = (idx >> 12) & 15;
  int b = idx >> 16;
  float A[4], st[4];
  size_t pbase = (((size_t)((b * 16 + c) * 16 + sh * 4)) << 10) + d;
#pragma unroll
  for (int s = 0; s < 4; ++s) {
    A[s] = -__expf(Alog[d * 16 + sh * 4 + s]);
    st[s] = scrL[pbase + ((size_t)s << 10)];
  }
  float Dv = Dp[d];
  int t0 = c * CLEN;
  size_t base = (((size_t)(b * 1024 + t0)) << 10) + d;
  size_t zoff = ((((size_t)(b * 1024 + t0)) << 11)) + 1024 + d;
  const float* xb = xdb + (size_t)(b * 1024 + t0) * 64 + 32 + sh * 4;
  float dtv = bf2f(dt[base]), xv = bf2f(xc[base]), zv = bf2f(xz[zoff]);
  for (int t = 0; t < CLEN; ++t) {
    float dtn = 0.f, xvn = 0.f, zvn = 0.f;
    if (t + 1 < CLEN) {
      dtn = bf2f(dt[base + 1024]); xvn = bf2f(xc[base + 1024]); zvn = bf2f(xz[zoff + 2048]);
    }
    float4 Bv = *(const float4*)xb;
    float4 Cv = *(const float4*)(xb + 16);
    float dx = dtv * xv;
    float e0 = __expf(dtv * A[0]), e1 = __expf(dtv * A[1]);
    float e2 = __expf(dtv * A[2]), e3 = __expf(dtv * A[3]);
    st[0] = st[0] * e0 + dx * Bv.x;
    st[1] = st[1] * e1 + dx * Bv.y;
    st[2] = st[2] * e2 + dx * Bv.z;
    st[3] = st[3] * e3 + dx * Bv.w;
    float acc = st[0] * Cv.x + st[1] * Cv.y + st[2] * Cv.z + st[3] * Cv.w;
    acc += __shfl_xor(acc, 1);
    acc += __shfl_xor(acc, 2);
    if (sh == 0)
      ybf[base] = f2bf((acc + Dv * xv) * silu_f(zv));
    base += 1024; zoff += 2048; xb += 64;
    dtv = dtn; xv = xvn; zv = zvn;
  }
}

// ---------------------------------------------------------------------------
// Residual + LayerNorm. add / out_bf may be nullptr.
// ---------------------------------------------------------------------------
__global__ __launch_bounds__(128) void resid_ln_kernel(const float* __restrict__ x,
                                                       const float* __restrict__ add,
                                                       const float* __restrict__ w,
                                                       const float* __restrict__ bias,
                                                       float* __restrict__ out,
                                                       ushort_t* __restrict__ out_bf) {
  int row = blockIdx.x, tid = threadIdx.x;
  float4 v = ((const float4*)(x + (size_t)row * 512))[tid];
  if (add) {
    float4 a = ((const float4*)(add + (size_t)row * 512))[tid];
    v.x += a.x; v.y += a.y; v.z += a.z; v.w += a.w;
  }
  float s = v.x + v.y + v.z + v.w;
  float ss = v.x * v.x + v.y * v.y + v.z * v.z + v.w * v.w;
#pragma unroll
  for (int o = 32; o; o >>= 1) {
    s += __shfl_xor(s, o);
    ss += __shfl_xor(ss, o);
  }
  __shared__ float red[4];
  int wid = tid >> 6;
  if ((tid & 63) == 0) { red[wid] = s; red[2 + wid] = ss; }
  __syncthreads();
  s = red[0] + red[1];
  ss = red[2] + red[3];
  float mean = s * (1.f / 512.f);
  float var = ss * (1.f / 512.f) - mean * mean;
  float inv = rsqrtf(var + 1e-5f);
  float4 wv = ((const float4*)w)[tid];
  float4 bv = ((const float4*)bias)[tid];
  float4 ov;
  ov.x = (v.x - mean) * inv * wv.x + bv.x;
  ov.y = (v.y - mean) * inv * wv.y + bv.y;
  ov.z = (v.z - mean) * inv * wv.z + bv.z;
  ov.w = (v.w - mean) * inv * wv.w + bv.w;
  ((float4*)(out + (size_t)row * 512))[tid] = ov;
  if (out_bf) {
    us4 ob = {f2bf(ov.x), f2bf(ov.y), f2bf(ov.z), f2bf(ov.w)};
    ((us4*)(out_bf + (size_t)row * 512))[tid] = ob;
  }
}

// ---------------------------------------------------------------------------
// Residual + split-K2 bf16 partial sum + optional gemm-bias + LayerNorm, fused.
// ---------------------------------------------------------------------------
__global__ __launch_bounds__(128) void resid_ln_sk(const float* __restrict__ x,
                                                   const ushort_t* __restrict__ p,
                                                   const float* __restrict__ pbias,
                                                   const float* __restrict__ w,
                                                   const float* __restrict__ bias,
                                                   float* __restrict__ out,
                                                   ushort_t* __restrict__ out_bf) {
  int row = blockIdx.x, tid = threadIdx.x;
  float4 v = ((const float4*)(x + (size_t)row * 512))[tid];
  us4 a = ((const us4*)(p + (size_t)row * 512))[tid];
  us4 c = ((const us4*)(p + 4194304 + (size_t)row * 512))[tid];
  v.x += bf2f(a.x) + bf2f(c.x);
  v.y += bf2f(a.y) + bf2f(c.y);
  v.z += bf2f(a.z) + bf2f(c.z);
  v.w += bf2f(a.w) + bf2f(c.w);
  if (pbias) {
    float4 pb = ((const float4*)pbias)[tid];
    v.x += pb.x; v.y += pb.y; v.z += pb.z; v.w += pb.w;
  }
  float s = v.x + v.y + v.z + v.w;
  float ss = v.x * v.x + v.y * v.y + v.z * v.z + v.w * v.w;
#pragma unroll
  for (int o = 32; o; o >>= 1) {
    s += __shfl_xor(s, o);
    ss += __shfl_xor(ss, o);
  }
  __shared__ float red[4];
  int wid = tid >> 6;
  if ((tid & 63) == 0) { red[wid] = s; red[2 + wid] = ss; }
  __syncthreads();
  s = red[0] + red[1];
  ss = red[2] + red[3];
  float mean = s * (1.f / 512.f);
  float var = ss * (1.f / 512.f) - mean * mean;
  float inv = rsqrtf(var + 1e-5f);
  float4 wv = ((const float4*)w)[tid];
  float4 bv = ((const float4*)bias)[tid];
  float4 ov;
  ov.x = (v.x - mean) * inv * wv.x + bv.x;
  ov.y = (v.y - mean) * inv * wv.y + bv.y;
  ov.z = (v.z - mean) * inv * wv.z + bv.z;
  ov.w = (v.w - mean) * inv * wv.w + bv.w;
  ((float4*)(out + (size_t)row * 512))[tid] = ov;
  us4 ob = {f2bf(ov.x), f2bf(ov.y), f2bf(ov.z), f2bf(ov.w)};
  ((us4*)(out_bf + (size_t)row * 512))[tid] = ob;
}

// ---------------------------------------------------------------------------
// Sinusoidal positional encoding add (in-place on h, refresh hbf)
// ---------------------------------------------------------------------------
__global__ __launch_bounds__(256) void posenc_kernel(float* __restrict__ h,
                                                     ushort_t* __restrict__ hbf) {
  int idx = blockIdx.x * 256 + threadIdx.x;
  int d = idx & 511;
  int l = (idx >> 9) & 1023;
  float freq = __expf(-(float)(d & ~1) * (9.210340371976184f / 512.f));
  float ang = (float)l * freq;
  float v = h[idx] + ((d & 1) ? cosf(ang) : sinf(ang));
  h[idx] = v;
  hbf[idx] = f2bf(v);
}

// ---------------------------------------------------------------------------
// MFMA flash attention (round-12 proven form: 64 VGPR, 72 us/dispatch).
// XCD-aware decode; QBLK=64, grid 1024; synchronous staging; truncating P.
// __launch_bounds__(256,8) pins VGPR <= 64.
// ---------------------------------------------------------------------------
__global__ __launch_bounds__(256, 8) void attn_mfma(const ushort_t* __restrict__ qkv,
                                                    ushort_t* __restrict__ ao) {
  __shared__ unsigned short Qs[4096];
  __shared__ unsigned short Ks[4096];
  __shared__ unsigned short Vt[4096];
  __shared__ unsigned short Ps[4096];
  const int tid = threadIdx.x;
  const int w = blockIdx.x;                      // 1024 blocks
  const int bh = (w & 7) + (w >> 7) * 8;         // b*8 + h (XCD w%8 keeps bh)
  const int qt = (w >> 3) & 15;
  const int hh = bh & 7, b = bh >> 3;
  const int l0 = qt * 64;
  const size_t bb = (size_t)b * 1024 * 1536;

  const int srow = tid >> 2;
  const int sdb = (tid & 3) << 4;
  const int sc0 = sdb >> 3;

  {
    const ushort_t* qp = qkv + bb + (size_t)(l0 + srow) * 1536 + hh * 64 + sdb;
    *(bfrag*)&Qs[srow * 64 + ((sc0 ^ (srow & 7)) << 3)] = *(const bfrag*)qp;
    *(bfrag*)&Qs[srow * 64 + (((sc0 + 1) ^ (srow & 7)) << 3)] = *(const bfrag*)(qp + 8);
  }

  const int wid = tid >> 6, lane = tid & 63;
  const int l15 = lane & 15, rg = lane >> 4;
  const int l7 = l15 & 7;
  float m[4], lsum[4];
  f32x4 oacc[4];
#pragma unroll
  for (int r = 0; r < 4; ++r) { m[r] = -1e30f; lsum[r] = 0.f; }
#pragma unroll
  for (int nt = 0; nt < 4; ++nt) oacc[nt] = (f32x4)(0.f);

  for (int jt = 0; jt < 16; ++jt) {
    {
      const ushort_t* kp = qkv + bb + (size_t)(jt * 64 + srow) * 1536 + hh * 64 + 512 + sdb;
      *(bfrag*)&Ks[srow * 64 + ((sc0 ^ (srow & 7)) << 3)] = *(const bfrag*)kp;
      *(bfrag*)&Ks[srow * 64 + (((sc0 + 1) ^ (srow & 7)) << 3)] = *(const bfrag*)(kp + 8);
      const ushort_t* vp = kp + 512;
      unsigned short vv[16];
      *(bfrag*)&vv[0] = *(const bfrag*)vp;
      *(bfrag*)&vv[8] = *(const bfrag*)(vp + 8);
#pragma unroll
      for (int j = 0; j < 16; ++j) {
        int dd = sdb + j;
        Vt[dd * 64 + (((srow >> 3) ^ (dd & 7) ^ ((dd >> 3) & 7)) << 3) + (srow & 7)] = vv[j];
      }
    }
    __syncthreads();

    bfrag aq[2];
#pragma unroll
    for (int ks = 0; ks < 2; ++ks)
      aq[ks] = *(const bfrag*)&Qs[(wid * 16 + l15) * 64 + (((ks * 4 + rg) ^ l7) << 3)];
    f32x4 sc[4];
#pragma unroll
    for (int nt = 0; nt < 4; ++nt) {
      f32x4 s = (f32x4)(0.f);
#pragma unroll
      for (int ks = 0; ks < 2; ++ks) {
        bfrag bk = *(const bfrag*)&Ks[(nt * 16 + l15) * 64 + (((ks * 4 + rg) ^ l7) << 3)];
        s = __builtin_amdgcn_mfma_f32_16x16x32_bf16(aq[ks], bk, s, 0, 0, 0);
      }
      sc[nt] = s * 0.125f;
    }

#pragma unroll
    for (int r = 0; r < 4; ++r) {
      float mc = fmaxf(fmaxf(sc[0][r], sc[1][r]), fmaxf(sc[2][r], sc[3][r]));
#pragma unroll
      for (int o = 8; o; o >>= 1) mc = fmaxf(mc, __shfl_xor(mc, o));
      float mn = fmaxf(m[r], mc);
      float al = __expf(m[r] - mn);
      m[r] = mn;
      int prow = rg * 4 + r;
      float ps = 0.f;
#pragma unroll
      for (int nt = 0; nt < 4; ++nt) {
        float p = __expf(sc[nt][r] - mn);
        ps += p;
        int col = nt * 16 + l15;
        Ps[wid * 1024 + prow * 64 + ((((col >> 3) ^ (prow & 7))) << 3) + (col & 7)] =
            (ushort_t)(__float_as_uint(p) >> 16);   // truncating bf16
      }
#pragma unroll
      for (int o = 8; o; o >>= 1) ps += __shfl_xor(ps, o);
      lsum[r] = lsum[r] * al + ps;
#pragma unroll
      for (int nt = 0; nt < 4; ++nt) oacc[nt][r] *= al;
    }

    bfrag ap[2];
#pragma unroll
    for (int ks = 0; ks < 2; ++ks)
      ap[ks] = *(const bfrag*)&Ps[wid * 1024 + l15 * 64 + (((ks * 4 + rg) ^ l7) << 3)];
#pragma unroll
    for (int nt = 0; nt < 4; ++nt) {
      int vrow = nt * 16 + l15;
#pragma unroll
      for (int ks = 0; ks < 2; ++ks) {
        bfrag bv = *(const bfrag*)&Vt[vrow * 64 +
            (((ks * 4 + rg) ^ (vrow & 7) ^ ((vrow >> 3) & 7)) << 3)];
        oacc[nt] = __builtin_amdgcn_mfma_f32_16x16x32_bf16(ap[ks], bv, oacc[nt], 0, 0, 0);
      }
    }
    __syncthreads();
  }

#pragma unroll
  for (int r = 0; r < 4; ++r) {
    float inv = 1.f / lsum[r];
    int row = l0 + wid * 16 + rg * 4 + r;
    ushort_t* op = ao + ((size_t)(b * 1024 + row)) * 512 + hh * 64;
#pragma unroll
    for (int nt = 0; nt < 4; ++nt) op[nt * 16 + l15] = f2bf(oacc[nt][r] * inv);
  }
}

// ---------------------------------------------------------------------------
// Mean over L, two-pass.
// ---------------------------------------------------------------------------
__global__ __launch_bounds__(512) void mean_part(const float* __restrict__ h,
                                                 float* __restrict__ part) {
  int blk = blockIdx.x;                       // b*16 + lc
  int b = blk >> 4, lc = blk & 15, d = threadIdx.x;
  float s = 0.f;
  int l0 = lc * 64;
  for (int l = l0; l < l0 + 64; ++l) s += h[(((size_t)(b * 1024 + l)) << 9) + d];
  part[((size_t)blk << 9) + d] = s;
}
__global__ __launch_bounds__(256) void mean_final(const float* __restrict__ part,
                                                  float* __restrict__ out2) {
  int i = blockIdx.x * 256 + threadIdx.x;     // b*512 + d
  int b = i >> 9, d = i & 511;
  float s = 0.f;
#pragma unroll
  for (int c = 0; c < 16; ++c) s += part[(((size_t)(b * 16 + c)) << 9) + d];
  out2[i] = s * (1.f / 1024.f);
}

// ---------------------------------------------------------------------------
extern "C" void kernel_launch(void* const* d_in, const int* in_sizes, int n_in,
                              void* d_out, int out_size, void* d_ws, size_t ws_size,
                              hipStream_t stream) {
  const float* x        = (const float*)d_in[0];
  const float* proj_w   = (const float*)d_in[1];
  const float* proj_b   = (const float*)d_in[2];
  const float* m_in_w   = (const float*)d_in[3];
  const float* m_conv_w = (const float*)d_in[4];
  const float* m_conv_b = (const float*)d_in[5];
  const float* m_xproj_w= (const float*)d_in[6];
  const float* m_dt_w   = (const float*)d_in[7];
  const float* m_dt_b   = (const float*)d_in[8];
  const float* m_Alog   = (const float*)d_in[9];
  const float* m_D      = (const float*)d_in[10];
  const float* m_out_w  = (const float*)d_in[11];
  const float* m_ln_w   = (const float*)d_in[12];
  const float* m_ln_b   = (const float*)d_in[13];
  const float* t_qkv_w  = (const float*)d_in[14];
  const float* t_qkv_b  = (const float*)d_in[15];
  const float* t_ow     = (const float*)d_in[16];
  const float* t_ob     = (const float*)d_in[17];
  const float* t_l1w    = (const float*)d_in[18];
  const float* t_l1b    = (const float*)d_in[19];
  const float* t_l2w    = (const float*)d_in[20];
  const float* t_l2b    = (const float*)d_in[21];
  const float* t_ln1w   = (const float*)d_in[22];
  const float* t_ln1b   = (const float*)d_in[23];
  const float* t_ln2w   = (const float*)d_in[24];
  const float* t_ln2b   = (const float*)d_in[25];
  const float* no_w     = (const float*)d_in[26];
  const float* no_b     = (const float*)d_in[27];

  float* ws   = (float*)d_ws;
  float* h    = ws;                                   //  4M f
  ushort_t* h_bf = (ushort_t*)(ws + 4194304);         //  4M us (2M f)
  float* bufA = ws + 6291456;                         // 16M f (xz_bf / qkv_bf / ff1_bf)
  float* bufB = bufA + 16777216;                      //  8M f (xc_bf / ao_bf)
  float* bufC = bufB + 8388608;                       //  8M f (xproj partials / dt_bf / split-K partials)
  float* bufE = bufC + 8388608;                       //  4M f (scan scratch)
  float* bufF = bufE + 4194304;                       //  0.5M f (xdb f32 / mean partials)
  ushort_t* y_bf = (ushort_t*)(bufF + 524288);        //  8M us (4M f)
  ushort_t* wbf  = (ushort_t*)(bufF + 524288 + 4194304);
  float* scrP = bufE;
  float* scrL = bufE + 2097152;

  // bf16 weight pool offsets (ushort units)
  ushort_t* wIN  = wbf;                 // 2 x 2048 x 512   = 2,097,152
  ushort_t* wOUT = wbf + 2097152;       // 2 x 512 x 1024   = 1,048,576
  ushort_t* wQKV = wbf + 3145728;       // 2 x 1536 x 512   = 1,572,864
  ushort_t* wOW  = wbf + 4718592;       // 2 x 512 x 512    =   524,288
  ushort_t* wL1  = wbf + 5242880;       // 2 x 2048 x 512   = 2,097,152
  ushort_t* wL2  = wbf + 7340032;       // 2 x 512 x 2048   = 2,097,152
  ushort_t* wXP  = wbf + 9437184;       // 2 x 64 x 1024    =   131,072
  ushort_t* wDT  = wbf + 9568256;       // 2 x 1024 x 32    =    65,536
  ushort_t* xdb_bf = wbf + 9633792;     // 8192 x 64        =   524,288

  Cvt8Args ca;
  ca.s[0] = m_in_w;    ca.d[0] = wIN;
  ca.s[1] = m_out_w;   ca.d[1] = wOUT;
  ca.s[2] = t_qkv_w;   ca.d[2] = wQKV;
  ca.s[3] = t_ow;      ca.d[3] = wOW;
  ca.s[4] = t_l1w;     ca.d[4] = wL1;
  ca.s[5] = t_l2w;     ca.d[5] = wL2;
  ca.s[6] = m_xproj_w; ca.d[6] = wXP;
  ca.s[7] = m_dt_w;    ca.d[7] = wDT;
  ca.end[0] = 2048; ca.end[1] = 3072; ca.end[2] = 4608; ca.end[3] = 5120;
  ca.end[4] = 7168; ca.end[5] = 9216; ca.end[6] = 9344; ca.end[7] = 9408;
  cvt8<<<9408, 256, 0, stream>>>(ca);

  proj_kernel<<<16384, 256, 0, stream>>>(x, proj_w, proj_b, h, h_bf);

  for (int i = 0; i < 2; ++i) {
    // xz = h @ in_w^T   (8192 x 2048, K=512) -> bf16
    gemm_gll<0, 1, 1, 128><<<dim3(16, 64), 256, 0, stream>>>(
        h_bf, wIN + (size_t)i * 1048576, nullptr, bufA, DMODEL, DMODEL, 2 * DINNER);
    // xc = silu(causal_conv(xm)) -> bf16 (2 ch/thread)
    conv_silu_kernel<<<16384, 256, 0, stream>>>((const unsigned*)bufA,
                                                m_conv_w + i * DINNER * 4,
                                                m_conv_b + i * DINNER, (unsigned*)bufB);
    // xdb = xc @ xp_w^T  (8192 x 64, K=1024), MFMA split-K=8 (fp32 partials)
    gemm_gll<0, 0, 8, 64><<<dim3(1, 64, 8), 256, 0, stream>>>(
        (const ushort_t*)bufB, wXP + (size_t)i * 65536, nullptr, bufC,
        DINNER, DINNER, 64);
    reduce8_xdb<<<512, 256, 0, stream>>>(bufC, bufF, xdb_bf);
    // dt = softplus(xdb[:, :32] @ dt_w^T + dt_b), MFMA K=32 -> bufC bf16
    gemm_gll<2, 1, 1, 128><<<dim3(8, 64), 256, 0, stream>>>(
        xdb_bf, wDT + (size_t)i * 32768, m_dt_b + i * DINNER, bufC,
        DTRANK, 64, DINNER);
    // chunked selective scan (state-split x4) -> y_bf (bf16)
    scan_pass1<<<2048, 256, 0, stream>>>((const ushort_t*)bufC, bufF, (const ushort_t*)bufB,
                                         m_Alog + (size_t)i * DINNER * DSTATE, scrP, scrL);
    scan_pass2<<<512, 256, 0, stream>>>(scrP, scrL);
    scan_pass3<<<2048, 256, 0, stream>>>((const ushort_t*)bufC, bufF, (const ushort_t*)bufB,
                                         (const ushort_t*)bufA, y_bf,
                                         m_Alog + (size_t)i * DINNER * DSTATE,
                                         m_D + i * DINNER, scrL);
    // mamba_out = y @ out_w^T  (8192 x 512, K=1024), split-K=2 bf16 partials
    gemm_gll<0, 1, 2, 128><<<dim3(4, 64, 2), 256, 0, stream>>>(
        y_bf, wOUT + (size_t)i * 524288, nullptr, bufC, DINNER, DINNER, DMODEL);
    resid_ln_sk<<<8192, 128, 0, stream>>>(h, (const ushort_t*)bufC, nullptr,
                                          m_ln_w + i * DMODEL, m_ln_b + i * DMODEL, h, h_bf);
  }

  posenc_kernel<<<16384, 256, 0, stream>>>(h, h_bf);

  for (int i = 0; i < 2; ++i) {
    // qkv = h @ qkv_w^T + qkv_b  (8192 x 1536, K=512) -> bf16
    gemm_gll<0, 1, 1, 128><<<dim3(12, 64), 256, 0, stream>>>(
        h_bf, wQKV + (size_t)i * 786432, t_qkv_b + i * 3 * DMODEL, bufA,
        DMODEL, DMODEL, 3 * DMODEL);
    // MFMA flash attention (XCD-swizzled) -> ao bf16
    attn_mfma<<<1024, 256, 0, stream>>>((const ushort_t*)bufA, (ushort_t*)bufB);
    // attn_proj = ao @ ow^T  (8192 x 512, K=512), split-K=2 bf16 partials
    gemm_gll<0, 1, 2, 128><<<dim3(4, 64, 2), 256, 0, stream>>>(
        (const ushort_t*)bufB, wOW + (size_t)i * 262144, nullptr, bufC,
        DMODEL, DMODEL, DMODEL);
    resid_ln_sk<<<8192, 128, 0, stream>>>(h, (const ushort_t*)bufC, t_ob + i * DMODEL,
                                          t_ln1w + i * DMODEL, t_ln1b + i * DMODEL, h, h_bf);
    // ff1 = relu(h @ l1w^T + l1b)  (8192 x 2048, K=512) -> bf16
    gemm_gll<1, 1, 1, 128><<<dim3(16, 64), 256, 0, stream>>>(
        h_bf, wL1 + (size_t)i * 1048576, t_l1b + i * DFF, bufA,
        DMODEL, DMODEL, DFF);
    // ff2 = ff1 @ l2w^T  (8192 x 512, K=2048), split-K=2 bf16 partials
    gemm_gll<0, 1, 2, 128><<<dim3(4, 64, 2), 256, 0, stream>>>(
        (const ushort_t*)bufA, wL2 + (size_t)i * 1048576, nullptr, bufC,
        DFF, DFF, DMODEL);
    resid_ln_sk<<<8192, 128, 0, stream>>>(h, (const ushort_t*)bufC, t_l2b + i * DMODEL,
                                          t_ln2w + i * DMODEL, t_ln2b + i * DMODEL, h, h_bf);
  }

  // final LN -> d_out, then mean over L -> d_out tail
  float* out_h = (float*)d_out;
  resid_ln_kernel<<<8192, 128, 0, stream>>>(h, nullptr, no_w, no_b, out_h, nullptr);
  mean_part<<<128, 512, 0, stream>>>(out_h, bufF);
  mean_final<<<16, 256, 0, stream>>>(bufF, out_h + 4194304);
}

// Round 15
// 932.329 us; speedup vs baseline: 1.2185x; 1.0111x over previous
//
#include <hip/hip_runtime.h>
#include <cstddef>

// Problem constants
#define BATCH 8
#define LSEQ 1024
#define DMODEL 512
#define DINNER 1024
#define DSTATE 16
#define DTRANK 32
#define NHEAD 8
#define DHEAD 64
#define DFF 2048
#define MTOK 8192   // BATCH*LSEQ
#define NCHUNK 16
#define CLEN 64     // LSEQ / NCHUNK

typedef __attribute__((ext_vector_type(8))) short bfrag;          // 8 bf16 = 16 B
typedef __attribute__((ext_vector_type(4))) float f32x4;          // MFMA acc
typedef __attribute__((ext_vector_type(4))) unsigned short us4;
typedef unsigned short ushort_t;

__device__ __forceinline__ float silu_f(float x) { return x / (1.f + __expf(-x)); }

__device__ __forceinline__ unsigned short f2bf(float f) {  // RNE fp32->bf16
  unsigned u = __float_as_uint(f);
  return (unsigned short)((u + 0x7FFFu + ((u >> 16) & 1u)) >> 16);
}
__device__ __forceinline__ float bf2f(ushort_t u) {
  return __uint_as_float((unsigned)u << 16);
}

// async global->LDS, 16B per lane. LDS dest = wave-uniform base + lane*16.
__device__ __forceinline__ void gll16(const ushort_t* g, ushort_t* l) {
  __builtin_amdgcn_global_load_lds(
      (const __attribute__((address_space(1))) unsigned int*)g,
      (__attribute__((address_space(3))) unsigned int*)l, 16, 0, 0);
}

// ---------------------------------------------------------------------------
// 8-segment fp32 -> bf16 weight convert (single launch).
// ---------------------------------------------------------------------------
struct Cvt8Args {
  const float* s[8];
  ushort_t* d[8];
  int end[8];   // prefix-sum of blocks
};
__global__ __launch_bounds__(256) void cvt8(Cvt8Args a) {
  int blk = blockIdx.x;
  int seg = 0, start = 0;
#pragma unroll
  for (int i = 0; i < 7; ++i)
    if (blk >= a.end[i]) { seg = i + 1; start = a.end[i]; }
  int i4 = (blk - start) * 256 + threadIdx.x;
  float4 v = ((const float4*)a.s[seg])[i4];
  us4 o = {f2bf(v.x), f2bf(v.y), f2bf(v.z), f2bf(v.w)};
  ((us4*)a.d[seg])[i4] = o;
}

// ---------------------------------------------------------------------------
// Input projection: h[b,l,d] = sum_c x[b,c,l] * pw[d,c] + pb[d]; also bf16 copy.
// ---------------------------------------------------------------------------
__global__ __launch_bounds__(256) void proj_kernel(const float* __restrict__ x,
                                                   const float* __restrict__ pw,
                                                   const float* __restrict__ pb,
                                                   float* __restrict__ h,
                                                   ushort_t* __restrict__ hbf) {
  int idx = blockIdx.x * 256 + threadIdx.x;        // ((b*L)+l)*512 + d
  int d = idx & 511;
  int l = (idx >> 9) & 1023;
  int b = idx >> 19;
  const float* xb = x + (size_t)b * 3 * 1024 + l;
  float v = pb[d] + xb[0] * pw[d * 3] + xb[1024] * pw[d * 3 + 1] + xb[2048] * pw[d * 3 + 2];
  h[idx] = v;
  hbf[idx] = f2bf(v);
}

// ---------------------------------------------------------------------------
// bf16 MFMA GEMM, global_load_lds + double-buffered prefetch.
// C[m,n] = act( sum_k A[m,k]*W[n,k] + bias[n] ).  Tile 128 x BN, BK=32.
// ACT: 0 none, 1 relu, 2 softplus. CBF: 1 bf16 C, 0 fp32 C.
// SPLITK: 1 direct; >1 -> partials at Cp + z*8192*ldc (no bias/act),
//   dtype of partials follows CBF (bf16 if CBF else fp32).
// ---------------------------------------------------------------------------
template <int ACT, int CBF, int SPLITK, int BN>
__global__ __launch_bounds__(256) void gemm_gll(const ushort_t* __restrict__ A,
                                                const ushort_t* __restrict__ W,
                                                const float* __restrict__ bias,
                                                void* __restrict__ Cp,
                                                int K, int lda, int ldc) {
  __shared__ ushort_t sA[2][4096];
  __shared__ ushort_t sB[2][BN * 32];
  constexpr int MREP = (BN == 128) ? 4 : 2;
  const int bm = blockIdx.y * 128, bn = blockIdx.x * BN;
  const int tid = threadIdx.x;
  const int wid = tid >> 6, lane = tid & 63;
  const int wrb = (BN == 128) ? (wid >> 1) * 64 : wid * 32;
  const int wcb = (BN == 128) ? (wid & 1) * 64 : 0;
  const int lr = lane & 15, ls = lane >> 4;
  const int sw = ls ^ ((lr >> 1) & 3);

  const int kseg = K / SPLITK;
  const int kbeg = (SPLITK > 1) ? blockIdx.z * kseg : 0;

  const int c0 = wid * 128 + lane;
  const int c1 = c0 + 64;
  const int r0 = c0 >> 2, s0 = (c0 & 3) ^ ((r0 >> 1) & 3);
  const int r1 = c1 >> 2, s1 = (c1 & 3) ^ ((r1 >> 1) & 3);
  const ushort_t* gA0 = A + (size_t)(bm + r0) * lda + kbeg + s0 * 8;
  const ushort_t* gA1 = A + (size_t)(bm + r1) * lda + kbeg + s1 * 8;
  const ushort_t* gB0;
  const ushort_t* gB1 = nullptr;
  if constexpr (BN == 128) {
    gB0 = W + (size_t)(bn + r0) * K + kbeg + s0 * 8;
    gB1 = W + (size_t)(bn + r1) * K + kbeg + s1 * 8;
  } else {
    const int cb = wid * 64 + lane;
    const int rb = cb >> 2, sb2 = (cb & 3) ^ ((rb >> 1) & 3);
    gB0 = W + (size_t)(bn + rb) * K + kbeg + sb2 * 8;
  }

  f32x4 acc[MREP][4];
#pragma unroll
  for (int i = 0; i < MREP; ++i)
#pragma unroll
    for (int j = 0; j < 4; ++j) acc[i][j] = (f32x4)(0.f);

#define STAGE(buf, step)                                             \
  do {                                                               \
    gll16(gA0 + (step) * 32, &sA[buf][wid * 1024]);                  \
    gll16(gA1 + (step) * 32, &sA[buf][wid * 1024 + 512]);            \
    if constexpr (BN == 128) {                                       \
      gll16(gB0 + (step) * 32, &sB[buf][wid * 1024]);                \
      gll16(gB1 + (step) * 32, &sB[buf][wid * 1024 + 512]);          \
    } else {                                                         \
      gll16(gB0 + (step) * 32, &sB[buf][wid * 512]);                 \
    }                                                                \
  } while (0)

  const int NT = kseg / 32;
  STAGE(0, 0);
  for (int t = 0; t < NT; ++t) {
    const int cur = t & 1;
    if (t + 1 < NT) {
      STAGE(cur ^ 1, t + 1);
      if constexpr (BN == 128)
        asm volatile("s_waitcnt vmcnt(4)" ::: "memory");
      else
        asm volatile("s_waitcnt vmcnt(3)" ::: "memory");
    } else {
      asm volatile("s_waitcnt vmcnt(0)" ::: "memory");
    }
    __builtin_amdgcn_sched_barrier(0);
    __builtin_amdgcn_s_barrier();
    __builtin_amdgcn_sched_barrier(0);

    bfrag af[MREP], bf[4];
#pragma unroll
    for (int mi = 0; mi < MREP; ++mi) {
      int row = wrb + mi * 16 + lr;
      af[mi] = *(const bfrag*)&sA[cur][(size_t)((row << 2) + sw) * 8];
    }
#pragma unroll
    for (int nj = 0; nj < 4; ++nj) {
      int col = wcb + nj * 16 + lr;
      bf[nj] = *(const bfrag*)&sB[cur][(size_t)((col << 2) + sw) * 8];
    }
#pragma unroll
    for (int mi = 0; mi < MREP; ++mi)
#pragma unroll
      for (int nj = 0; nj < 4; ++nj)
        acc[mi][nj] = __builtin_amdgcn_mfma_f32_16x16x32_bf16(af[mi], bf[nj], acc[mi][nj], 0, 0, 0);

    __builtin_amdgcn_s_barrier();
    __builtin_amdgcn_sched_barrier(0);
  }
#undef STAGE

  if (SPLITK > 1) {
#pragma unroll
    for (int nj = 0; nj < 4; ++nj) {
      int col = bn + wcb + nj * 16 + lr;
#pragma unroll
      for (int mi = 0; mi < MREP; ++mi) {
        int row0 = bm + wrb + mi * 16 + ls * 4;
#pragma unroll
        for (int r = 0; r < 4; ++r) {
          if (CBF)
            ((ushort_t*)Cp)[(size_t)blockIdx.z * 8192 * ldc +
                            (size_t)(row0 + r) * ldc + col] = f2bf(acc[mi][nj][r]);
          else
            ((float*)Cp)[(size_t)blockIdx.z * 8192 * ldc +
                         (size_t)(row0 + r) * ldc + col] = acc[mi][nj][r];
        }
      }
    }
  } else {
#pragma unroll
    for (int nj = 0; nj < 4; ++nj) {
      int col = bn + wcb + nj * 16 + lr;
      float bv = bias ? bias[col] : 0.f;
#pragma unroll
      for (int mi = 0; mi < MREP; ++mi) {
        int row0 = bm + wrb + mi * 16 + ls * 4;
#pragma unroll
        for (int r = 0; r < 4; ++r) {
          float v = acc[mi][nj][r] + bv;
          if (ACT == 1) v = fmaxf(v, 0.f);
          if (ACT == 2) v = (v > 20.f) ? v : log1pf(__expf(v));
          if (CBF)
            ((ushort_t*)Cp)[(size_t)(row0 + r) * ldc + col] = f2bf(v);
          else
            ((float*)Cp)[(size_t)(row0 + r) * ldc + col] = v;
        }
      }
    }
  }
}

// ---------------------------------------------------------------------------
// split-K=8 reduce for xproj: xdb fp32 + bf16 copy. 131072 float4 groups.
// ---------------------------------------------------------------------------
__global__ __launch_bounds__(256) void reduce8_xdb(const float* __restrict__ p,
                                                   float* __restrict__ xdb,
                                                   ushort_t* __restrict__ xdb_bf) {
  int i = blockIdx.x * 256 + threadIdx.x;
  float4 a = ((const float4*)p)[i];
#pragma unroll
  for (int z = 1; z < 8; ++z) {
    float4 b = ((const float4*)p)[i + z * 131072];
    a.x += b.x; a.y += b.y; a.z += b.z; a.w += b.w;
  }
  ((float4*)xdb)[i] = a;
  us4 o = {f2bf(a.x), f2bf(a.y), f2bf(a.z), f2bf(a.w)};
  ((us4*)xdb_bf)[i] = o;
}

// ---------------------------------------------------------------------------
// Depthwise causal conv (width 4) + SiLU, 2 channels/thread (u32 packed bf16).
// ---------------------------------------------------------------------------
__global__ __launch_bounds__(256) void conv_silu_kernel(const unsigned* __restrict__ xz,
                                                        const float* __restrict__ cw,
                                                        const float* __restrict__ cb,
                                                        unsigned* __restrict__ xc) {
  int idx = blockIdx.x * 256 + threadIdx.x;        // ((b*L)+t)*512 + dp
  int dp = idx & 511;
  int t = (idx >> 9) & 1023;
  int b = idx >> 19;
  int d0 = dp * 2;
  float a0 = cb[d0], a1 = cb[d0 + 1];
#pragma unroll
  for (int w = 0; w < 4; ++w) {
    int tt = t - 3 + w;
    if (tt >= 0) {
      unsigned v = xz[(((size_t)(b * 1024 + tt)) << 10) + dp];
      a0 += bf2f((ushort_t)(v & 0xffff)) * cw[d0 * 4 + w];
      a1 += bf2f((ushort_t)(v >> 16)) * cw[(d0 + 1) * 4 + w];
    }
  }
  unsigned o = (unsigned)f2bf(silu_f(a0)) | ((unsigned)f2bf(silu_f(a1)) << 16);
  xc[(((size_t)(b * 1024 + t)) << 9) + dp] = o;
}

// ---------------------------------------------------------------------------
// Chunked selective scan, STATE-SPLIT x4. xc, dt bf16.
// Pass1: P computed at chunk end as exp(A * sum(dt)).
// ---------------------------------------------------------------------------
__global__ __launch_bounds__(256) void scan_pass1(const ushort_t* __restrict__ dt,
                                                  const float* __restrict__ xdb,
                                                  const ushort_t* __restrict__ xc,
                                                  const float* __restrict__ Alog,
                                                  float* __restrict__ scrP,
                                                  float* __restrict__ scrL) {
  int idx = blockIdx.x * 256 + threadIdx.x;
  int sh = idx & 3;
  int d = (idx >> 2) & 1023;
  int c = (idx >> 12) & 15;
  int b = idx >> 16;
  float A[4], st[4];
#pragma unroll
  for (int s = 0; s < 4; ++s) {
    A[s] = -__expf(Alog[d * 16 + sh * 4 + s]);
    st[s] = 0.f;
  }
  float dtsum = 0.f;
  int t0 = c * CLEN;
  size_t base = (((size_t)(b * 1024 + t0)) << 10) + d;
  const float* xb = xdb + (size_t)(b * 1024 + t0) * 64 + 32 + sh * 4;
  float dtv = bf2f(dt[base]), xv = bf2f(xc[base]);
  for (int t = 0; t < CLEN; ++t) {
    float dtn = 0.f, xvn = 0.f;
    if (t + 1 < CLEN) { dtn = bf2f(dt[base + 1024]); xvn = bf2f(xc[base + 1024]); }
    float4 Bv = *(const float4*)xb;
    float dx = dtv * xv;
    float e0 = __expf(dtv * A[0]), e1 = __expf(dtv * A[1]);
    float e2 = __expf(dtv * A[2]), e3 = __expf(dtv * A[3]);
    st[0] = st[0] * e0 + dx * Bv.x;
    st[1] = st[1] * e1 + dx * Bv.y;
    st[2] = st[2] * e2 + dx * Bv.z;
    st[3] = st[3] * e3 + dx * Bv.w;
    dtsum += dtv;
    base += 1024; xb += 64;
    dtv = dtn; xv = xvn;
  }
  size_t pbase = (((size_t)((b * 16 + c) * 16 + sh * 4)) << 10) + d;
#pragma unroll
  for (int s = 0; s < 4; ++s) {
    scrP[pbase + ((size_t)s << 10)] = __expf(A[s] * dtsum);
    scrL[pbase + ((size_t)s << 10)] = st[s];
  }
}

// ---------------------------------------------------------------------------
// Pass 2: combine chunks serially per (b,d,s).
// ---------------------------------------------------------------------------
__global__ __launch_bounds__(256) void scan_pass2(const float* __restrict__ scrP,
                                                  float* __restrict__ scrL) {
  int idx = blockIdx.x * 256 + threadIdx.x;        // ((b*16 + s)*1024 + d)
  int d = idx & 1023;
  int s = (idx >> 10) & 15;
  int b = idx >> 14;
  float cur = 0.f;
  for (int c = 0; c < 16; ++c) {
    size_t o = (((size_t)(((b * 16 + c) * 16) + s)) << 10) + d;
    float P = scrP[o];
    float loc = scrL[o];
    scrL[o] = cur;
    cur = cur * P + loc;
  }
}

// ---------------------------------------------------------------------------
// Pass 3: state-split x4 rescan; quad-reduce via shfl_xor; bf16 y out.
// ---------------------------------------------------------------------------
__global__ __launch_bounds__(256) void scan_pass3(const ushort_t* __restrict__ dt,
                                                  const float* __restrict__ xdb,
                                                  const ushort_t* __restrict__ xc,
                                                  const ushort_t* __restrict__ xz,
                                                  ushort_t* __restrict__ ybf,
                                                  const float* __restrict__ Alog,
                                                  const float* __restrict__ Dp,
                                                  const float* __restrict__ scrL) {
  int idx = blockIdx.x * 256 + threadIdx.x;
  int sh = idx & 3;
  int d = (idx >> 2) & 1023;
  int c = (idx >> 12) & 15;
  int b = idx >> 16;
  float A[4], st[4];
  size_t pbase = (((size_t)((b * 16 + c) * 16 + sh * 4)) << 10) + d;
#pragma unroll
  for (int s = 0; s < 4; ++s) {
    A[s] = -__expf(Alog[d * 16 + sh * 4 + s]);
    st[s] = scrL[pbase + ((size_t)s << 10)];
  }
  float Dv = Dp[d];
  int t0 = c * CLEN;
  size_t base = (((size_t)(b * 1024 + t0)) << 10) + d;
  size_t zoff = ((((size_t)(b * 1024 + t0)) << 11)) + 1024 + d;
  const float* xb = xdb + (size_t)(b * 1024 + t0) * 64 + 32 + sh * 4;
  float dtv = bf2f(dt[base]), xv = bf2f(xc[base]), zv = bf2f(xz[zoff]);
  for (int t = 0; t < CLEN; ++t) {
    float dtn = 0.f, xvn = 0.f, zvn = 0.f;
    if (t + 1 < CLEN) {
      dtn = bf2f(dt[base + 1024]); xvn = bf2f(xc[base + 1024]); zvn = bf2f(xz[zoff + 2048]);
    }
    float4 Bv = *(const float4*)xb;
    float4 Cv = *(const float4*)(xb + 16);
    float dx = dtv * xv;
    float e0 = __expf(dtv * A[0]), e1 = __expf(dtv * A[1]);
    float e2 = __expf(dtv * A[2]), e3 = __expf(dtv * A[3]);
    st[0] = st[0] * e0 + dx * Bv.x;
    st[1] = st[1] * e1 + dx * Bv.y;
    st[2] = st[2] * e2 + dx * Bv.z;
    st[3] = st[3] * e3 + dx * Bv.w;
    float acc = st[0] * Cv.x + st[1] * Cv.y + st[2] * Cv.z + st[3] * Cv.w;
    acc += __shfl_xor(acc, 1);
    acc += __shfl_xor(acc, 2);
    if (sh == 0)
      ybf[base] = f2bf((acc + Dv * xv) * silu_f(zv));
    base += 1024; zoff += 2048; xb += 64;
    dtv = dtn; xv = xvn; zv = zvn;
  }
}

// ---------------------------------------------------------------------------
// Residual + LayerNorm. add / out_bf may be nullptr.
// ---------------------------------------------------------------------------
__global__ __launch_bounds__(128) void resid_ln_kernel(const float* __restrict__ x,
                                                       const float* __restrict__ add,
                                                       const float* __restrict__ w,
                                                       const float* __restrict__ bias,
                                                       float* __restrict__ out,
                                                       ushort_t* __restrict__ out_bf) {
  int row = blockIdx.x, tid = threadIdx.x;
  float4 v = ((const float4*)(x + (size_t)row * 512))[tid];
  if (add) {
    float4 a = ((const float4*)(add + (size_t)row * 512))[tid];
    v.x += a.x; v.y += a.y; v.z += a.z; v.w += a.w;
  }
  float s = v.x + v.y + v.z + v.w;
  float ss = v.x * v.x + v.y * v.y + v.z * v.z + v.w * v.w;
#pragma unroll
  for (int o = 32; o; o >>= 1) {
    s += __shfl_xor(s, o);
    ss += __shfl_xor(ss, o);
  }
  __shared__ float red[4];
  int wid = tid >> 6;
  if ((tid & 63) == 0) { red[wid] = s; red[2 + wid] = ss; }
  __syncthreads();
  s = red[0] + red[1];
  ss = red[2] + red[3];
  float mean = s * (1.f / 512.f);
  float var = ss * (1.f / 512.f) - mean * mean;
  float inv = rsqrtf(var + 1e-5f);
  float4 wv = ((const float4*)w)[tid];
  float4 bv = ((const float4*)bias)[tid];
  float4 ov;
  ov.x = (v.x - mean) * inv * wv.x + bv.x;
  ov.y = (v.y - mean) * inv * wv.y + bv.y;
  ov.z = (v.z - mean) * inv * wv.z + bv.z;
  ov.w = (v.w - mean) * inv * wv.w + bv.w;
  ((float4*)(out + (size_t)row * 512))[tid] = ov;
  if (out_bf) {
    us4 ob = {f2bf(ov.x), f2bf(ov.y), f2bf(ov.z), f2bf(ov.w)};
    ((us4*)(out_bf + (size_t)row * 512))[tid] = ob;
  }
}

// ---------------------------------------------------------------------------
// Residual + split-K2 bf16 partial sum + optional gemm-bias + LayerNorm, fused.
// add_pe: add sinusoidal positional encoding AFTER the LN (fused posenc).
// ---------------------------------------------------------------------------
__global__ __launch_bounds__(128) void resid_ln_sk(const float* __restrict__ x,
                                                   const ushort_t* __restrict__ p,
                                                   const float* __restrict__ pbias,
                                                   const float* __restrict__ w,
                                                   const float* __restrict__ bias,
                                                   float* __restrict__ out,
                                                   ushort_t* __restrict__ out_bf,
                                                   int add_pe) {
  int row = blockIdx.x, tid = threadIdx.x;
  float4 v = ((const float4*)(x + (size_t)row * 512))[tid];
  us4 a = ((const us4*)(p + (size_t)row * 512))[tid];
  us4 c = ((const us4*)(p + 4194304 + (size_t)row * 512))[tid];
  v.x += bf2f(a.x) + bf2f(c.x);
  v.y += bf2f(a.y) + bf2f(c.y);
  v.z += bf2f(a.z) + bf2f(c.z);
  v.w += bf2f(a.w) + bf2f(c.w);
  if (pbias) {
    float4 pb = ((const float4*)pbias)[tid];
    v.x += pb.x; v.y += pb.y; v.z += pb.z; v.w += pb.w;
  }
  float s = v.x + v.y + v.z + v.w;
  float ss = v.x * v.x + v.y * v.y + v.z * v.z + v.w * v.w;
#pragma unroll
  for (int o = 32; o; o >>= 1) {
    s += __shfl_xor(s, o);
    ss += __shfl_xor(ss, o);
  }
  __shared__ float red[4];
  int wid = tid >> 6;
  if ((tid & 63) == 0) { red[wid] = s; red[2 + wid] = ss; }
  __syncthreads();
  s = red[0] + red[1];
  ss = red[2] + red[3];
  float mean = s * (1.f / 512.f);
  float var = ss * (1.f / 512.f) - mean * mean;
  float inv = rsqrtf(var + 1e-5f);
  float4 wv = ((const float4*)w)[tid];
  float4 bv = ((const float4*)bias)[tid];
  float4 ov;
  ov.x = (v.x - mean) * inv * wv.x + bv.x;
  ov.y = (v.y - mean) * inv * wv.y + bv.y;
  ov.z = (v.z - mean) * inv * wv.z + bv.z;
  ov.w = (v.w - mean) * inv * wv.w + bv.w;
  if (add_pe) {
    int l = row & 1023;
    int d0 = tid * 4;
    float f0 = __expf(-(float)d0 * (9.210340371976184f / 512.f));
    float f2 = __expf(-(float)(d0 + 2) * (9.210340371976184f / 512.f));
    float a0 = (float)l * f0, a2 = (float)l * f2;
    ov.x += sinf(a0); ov.y += cosf(a0);
    ov.z += sinf(a2); ov.w += cosf(a2);
  }
  ((float4*)(out + (size_t)row * 512))[tid] = ov;
  us4 ob = {f2bf(ov.x), f2bf(ov.y), f2bf(ov.z), f2bf(ov.w)};
  ((us4*)(out_bf + (size_t)row * 512))[tid] = ob;
}

// ---------------------------------------------------------------------------
// MFMA flash attention (r12 form + Ps swizzle fix).
// XCD-aware decode; QBLK=64, grid 1024; truncating P store.
// Ps chunk swizzle adds ^(((row>>3)&1)<<1) so all 4 rg groups hit distinct
// bank octets (was 4-way aliased). __launch_bounds__(256,8) pins VGPR <= 64.
// ---------------------------------------------------------------------------
__global__ __launch_bounds__(256, 8) void attn_mfma(const ushort_t* __restrict__ qkv,
                                                    ushort_t* __restrict__ ao) {
  __shared__ unsigned short Qs[4096];
  __shared__ unsigned short Ks[4096];
  __shared__ unsigned short Vt[4096];
  __shared__ unsigned short Ps[4096];
  const int tid = threadIdx.x;
  const int w = blockIdx.x;                      // 1024 blocks
  const int bh = (w & 7) + (w >> 7) * 8;         // b*8 + h (XCD w%8 keeps bh)
  const int qt = (w >> 3) & 15;
  const int hh = bh & 7, b = bh >> 3;
  const int l0 = qt * 64;
  const size_t bb = (size_t)b * 1024 * 1536;

  const int srow = tid >> 2;
  const int sdb = (tid & 3) << 4;
  const int sc0 = sdb >> 3;

  {
    const ushort_t* qp = qkv + bb + (size_t)(l0 + srow) * 1536 + hh * 64 + sdb;
    *(bfrag*)&Qs[srow * 64 + ((sc0 ^ (srow & 7)) << 3)] = *(const bfrag*)qp;
    *(bfrag*)&Qs[srow * 64 + (((sc0 + 1) ^ (srow & 7)) << 3)] = *(const bfrag*)(qp + 8);
  }

  const int wid = tid >> 6, lane = tid & 63;
  const int l15 = lane & 15, rg = lane >> 4;
  const int l7 = l15 & 7;
  float m[4], lsum[4];
  f32x4 oacc[4];
#pragma unroll
  for (int r = 0; r < 4; ++r) { m[r] = -1e30f; lsum[r] = 0.f; }
#pragma unroll
  for (int nt = 0; nt < 4; ++nt) oacc[nt] = (f32x4)(0.f);

  for (int jt = 0; jt < 16; ++jt) {
    {
      const ushort_t* kp = qkv + bb + (size_t)(jt * 64 + srow) * 1536 + hh * 64 + 512 + sdb;
      *(bfrag*)&Ks[srow * 64 + ((sc0 ^ (srow & 7)) << 3)] = *(const bfrag*)kp;
      *(bfrag*)&Ks[srow * 64 + (((sc0 + 1) ^ (srow & 7)) << 3)] = *(const bfrag*)(kp + 8);
      const ushort_t* vp = kp + 512;
      unsigned short vv[16];
      *(bfrag*)&vv[0] = *(const bfrag*)vp;
      *(bfrag*)&vv[8] = *(const bfrag*)(vp + 8);
#pragma unroll
      for (int j = 0; j < 16; ++j) {
        int dd = sdb + j;
        Vt[dd * 64 + (((srow >> 3) ^ (dd & 7) ^ ((dd >> 3) & 7)) << 3) + (srow & 7)] = vv[j];
      }
    }
    __syncthreads();

    bfrag aq[2];
#pragma unroll
    for (int ks = 0; ks < 2; ++ks)
      aq[ks] = *(const bfrag*)&Qs[(wid * 16 + l15) * 64 + (((ks * 4 + rg) ^ l7) << 3)];
    f32x4 sc[4];
#pragma unroll
    for (int nt = 0; nt < 4; ++nt) {
      f32x4 s = (f32x4)(0.f);
#pragma unroll
      for (int ks = 0; ks < 2; ++ks) {
        bfrag bk = *(const bfrag*)&Ks[(nt * 16 + l15) * 64 + (((ks * 4 + rg) ^ l7) << 3)];
        s = __builtin_amdgcn_mfma_f32_16x16x32_bf16(aq[ks], bk, s, 0, 0, 0);
      }
      sc[nt] = s * 0.125f;
    }

#pragma unroll
    for (int r = 0; r < 4; ++r) {
      float mc = fmaxf(fmaxf(sc[0][r], sc[1][r]), fmaxf(sc[2][r], sc[3][r]));
#pragma unroll
      for (int o = 8; o; o >>= 1) mc = fmaxf(mc, __shfl_xor(mc, o));
      float mn = fmaxf(m[r], mc);
      float al = __expf(m[r] - mn);
      m[r] = mn;
      int prow = rg * 4 + r;
      float ps = 0.f;
#pragma unroll
      for (int nt = 0; nt < 4; ++nt) {
        float p = __expf(sc[nt][r] - mn);
        ps += p;
        int col = nt * 16 + l15;
        int chunk = (col >> 3) ^ (prow & 7) ^ (((prow >> 3) & 1) << 1);
        Ps[wid * 1024 + prow * 64 + (chunk << 3) + (col & 7)] =
            (ushort_t)(__float_as_uint(p) >> 16);   // truncating bf16
      }
#pragma unroll
      for (int o = 8; o; o >>= 1) ps += __shfl_xor(ps, o);
      lsum[r] = lsum[r] * al + ps;
#pragma unroll
      for (int nt = 0; nt < 4; ++nt) oacc[nt][r] *= al;
    }

    bfrag ap[2];
#pragma unroll
    for (int ks = 0; ks < 2; ++ks) {
      int chunk = (ks * 4 + rg) ^ l7 ^ (((l15 >> 3) & 1) << 1);
      ap[ks] = *(const bfrag*)&Ps[wid * 1024 + l15 * 64 + (chunk << 3)];
    }
#pragma unroll
    for (int nt = 0; nt < 4; ++nt) {
      int vrow = nt * 16 + l15;
#pragma unroll
      for (int ks = 0; ks < 2; ++ks) {
        bfrag bv = *(const bfrag*)&Vt[vrow * 64 +
            (((ks * 4 + rg) ^ (vrow & 7) ^ ((vrow >> 3) & 7)) << 3)];
        oacc[nt] = __builtin_amdgcn_mfma_f32_16x16x32_bf16(ap[ks], bv, oacc[nt], 0, 0, 0);
      }
    }
    __syncthreads();
  }

#pragma unroll
  for (int r = 0; r < 4; ++r) {
    float inv = 1.f / lsum[r];
    int row = l0 + wid * 16 + rg * 4 + r;
    ushort_t* op = ao + ((size_t)(b * 1024 + row)) * 512 + hh * 64;
#pragma unroll
    for (int nt = 0; nt < 4; ++nt) op[nt * 16 + l15] = f2bf(oacc[nt][r] * inv);
  }
}

// ---------------------------------------------------------------------------
// Mean over L, two-pass.
// ---------------------------------------------------------------------------
__global__ __launch_bounds__(512) void mean_part(const float* __restrict__ h,
                                                 float* __restrict__ part) {
  int blk = blockIdx.x;                       // b*16 + lc
  int b = blk >> 4, lc = blk & 15, d = threadIdx.x;
  float s = 0.f;
  int l0 = lc * 64;
  for (int l = l0; l < l0 + 64; ++l) s += h[(((size_t)(b * 1024 + l)) << 9) + d];
  part[((size_t)blk << 9) + d] = s;
}
__global__ __launch_bounds__(256) void mean_final(const float* __restrict__ part,
                                                  float* __restrict__ out2) {
  int i = blockIdx.x * 256 + threadIdx.x;     // b*512 + d
  int b = i >> 9, d = i & 511;
  float s = 0.f;
#pragma unroll
  for (int c = 0; c < 16; ++c) s += part[(((size_t)(b * 16 + c)) << 9) + d];
  out2[i] = s * (1.f / 1024.f);
}

// ---------------------------------------------------------------------------
extern "C" void kernel_launch(void* const* d_in, const int* in_sizes, int n_in,
                              void* d_out, int out_size, void* d_ws, size_t ws_size,
                              hipStream_t stream) {
  const float* x        = (const float*)d_in[0];
  const float* proj_w   = (const float*)d_in[1];
  const float* proj_b   = (const float*)d_in[2];
  const float* m_in_w   = (const float*)d_in[3];
  const float* m_conv_w = (const float*)d_in[4];
  const float* m_conv_b = (const float*)d_in[5];
  const float* m_xproj_w= (const float*)d_in[6];
  const float* m_dt_w   = (const float*)d_in[7];
  const float* m_dt_b   = (const float*)d_in[8];
  const float* m_Alog   = (const float*)d_in[9];
  const float* m_D      = (const float*)d_in[10];
  const float* m_out_w  = (const float*)d_in[11];
  const float* m_ln_w   = (const float*)d_in[12];
  const float* m_ln_b   = (const float*)d_in[13];
  const float* t_qkv_w  = (const float*)d_in[14];
  const float* t_qkv_b  = (const float*)d_in[15];
  const float* t_ow     = (const float*)d_in[16];
  const float* t_ob     = (const float*)d_in[17];
  const float* t_l1w    = (const float*)d_in[18];
  const float* t_l1b    = (const float*)d_in[19];
  const float* t_l2w    = (const float*)d_in[20];
  const float* t_l2b    = (const float*)d_in[21];
  const float* t_ln1w   = (const float*)d_in[22];
  const float* t_ln1b   = (const float*)d_in[23];
  const float* t_ln2w   = (const float*)d_in[24];
  const float* t_ln2b   = (const float*)d_in[25];
  const float* no_w     = (const float*)d_in[26];
  const float* no_b     = (const float*)d_in[27];

  float* ws   = (float*)d_ws;
  float* h    = ws;                                   //  4M f
  ushort_t* h_bf = (ushort_t*)(ws + 4194304);         //  4M us (2M f)
  float* bufA = ws + 6291456;                         // 16M f (xz_bf / qkv_bf / ff1_bf)
  float* bufB = bufA + 16777216;                      //  8M f (xc_bf / ao_bf)
  float* bufC = bufB + 8388608;                       //  8M f (xproj partials / dt_bf / split-K partials)
  float* bufE = bufC + 8388608;                       //  4M f (scan scratch)
  float* bufF = bufE + 4194304;                       //  0.5M f (xdb f32 / mean partials)
  ushort_t* y_bf = (ushort_t*)(bufF + 524288);        //  8M us (4M f)
  ushort_t* wbf  = (ushort_t*)(bufF + 524288 + 4194304);
  float* scrP = bufE;
  float* scrL = bufE + 2097152;

  // bf16 weight pool offsets (ushort units)
  ushort_t* wIN  = wbf;                 // 2 x 2048 x 512   = 2,097,152
  ushort_t* wOUT = wbf + 2097152;       // 2 x 512 x 1024   = 1,048,576
  ushort_t* wQKV = wbf + 3145728;       // 2 x 1536 x 512   = 1,572,864
  ushort_t* wOW  = wbf + 4718592;       // 2 x 512 x 512    =   524,288
  ushort_t* wL1  = wbf + 5242880;       // 2 x 2048 x 512   = 2,097,152
  ushort_t* wL2  = wbf + 7340032;       // 2 x 512 x 2048   = 2,097,152
  ushort_t* wXP  = wbf + 9437184;       // 2 x 64 x 1024    =   131,072
  ushort_t* wDT  = wbf + 9568256;       // 2 x 1024 x 32    =    65,536
  ushort_t* xdb_bf = wbf + 9633792;     // 8192 x 64        =   524,288

  Cvt8Args ca;
  ca.s[0] = m_in_w;    ca.d[0] = wIN;
  ca.s[1] = m_out_w;   ca.d[1] = wOUT;
  ca.s[2] = t_qkv_w;   ca.d[2] = wQKV;
  ca.s[3] = t_ow;      ca.d[3] = wOW;
  ca.s[4] = t_l1w;     ca.d[4] = wL1;
  ca.s[5] = t_l2w;     ca.d[5] = wL2;
  ca.s[6] = m_xproj_w; ca.d[6] = wXP;
  ca.s[7] = m_dt_w;    ca.d[7] = wDT;
  ca.end[0] = 2048; ca.end[1] = 3072; ca.end[2] = 4608; ca.end[3] = 5120;
  ca.end[4] = 7168; ca.end[5] = 9216; ca.end[6] = 9344; ca.end[7] = 9408;
  cvt8<<<9408, 256, 0, stream>>>(ca);

  proj_kernel<<<16384, 256, 0, stream>>>(x, proj_w, proj_b, h, h_bf);

  for (int i = 0; i < 2; ++i) {
    // xz = h @ in_w^T   (8192 x 2048, K=512) -> bf16
    gemm_gll<0, 1, 1, 128><<<dim3(16, 64), 256, 0, stream>>>(
        h_bf, wIN + (size_t)i * 1048576, nullptr, bufA, DMODEL, DMODEL, 2 * DINNER);
    // xc = silu(causal_conv(xm)) -> bf16 (2 ch/thread)
    conv_silu_kernel<<<16384, 256, 0, stream>>>((const unsigned*)bufA,
                                                m_conv_w + i * DINNER * 4,
                                                m_conv_b + i * DINNER, (unsigned*)bufB);
    // xdb = xc @ xp_w^T  (8192 x 64, K=1024), MFMA split-K=8 (fp32 partials)
    gemm_gll<0, 0, 8, 64><<<dim3(1, 64, 8), 256, 0, stream>>>(
        (const ushort_t*)bufB, wXP + (size_t)i * 65536, nullptr, bufC,
        DINNER, DINNER, 64);
    reduce8_xdb<<<512, 256, 0, stream>>>(bufC, bufF, xdb_bf);
    // dt = softplus(xdb[:, :32] @ dt_w^T + dt_b), MFMA K=32 -> bufC bf16
    gemm_gll<2, 1, 1, 128><<<dim3(8, 64), 256, 0, stream>>>(
        xdb_bf, wDT + (size_t)i * 32768, m_dt_b + i * DINNER, bufC,
        DTRANK, 64, DINNER);
    // chunked selective scan (state-split x4) -> y_bf (bf16)
    scan_pass1<<<2048, 256, 0, stream>>>((const ushort_t*)bufC, bufF, (const ushort_t*)bufB,
                                         m_Alog + (size_t)i * DINNER * DSTATE, scrP, scrL);
    scan_pass2<<<512, 256, 0, stream>>>(scrP, scrL);
    scan_pass3<<<2048, 256, 0, stream>>>((const ushort_t*)bufC, bufF, (const ushort_t*)bufB,
                                         (const ushort_t*)bufA, y_bf,
                                         m_Alog + (size_t)i * DINNER * DSTATE,
                                         m_D + i * DINNER, scrL);
    // mamba_out = y @ out_w^T  (8192 x 512, K=1024), split-K=2 bf16 partials
    gemm_gll<0, 1, 2, 128><<<dim3(4, 64, 2), 256, 0, stream>>>(
        y_bf, wOUT + (size_t)i * 524288, nullptr, bufC, DINNER, DINNER, DMODEL);
    // h = LN(h + p0 + p1); posenc fused into layer-2's LN
    resid_ln_sk<<<8192, 128, 0, stream>>>(h, (const ushort_t*)bufC, nullptr,
                                          m_ln_w + i * DMODEL, m_ln_b + i * DMODEL,
                                          h, h_bf, i == 1 ? 1 : 0);
  }

  for (int i = 0; i < 2; ++i) {
    // qkv = h @ qkv_w^T + qkv_b  (8192 x 1536, K=512) -> bf16
    gemm_gll<0, 1, 1, 128><<<dim3(12, 64), 256, 0, stream>>>(
        h_bf, wQKV + (size_t)i * 786432, t_qkv_b + i * 3 * DMODEL, bufA,
        DMODEL, DMODEL, 3 * DMODEL);
    // MFMA flash attention (XCD-swizzled) -> ao bf16
    attn_mfma<<<1024, 256, 0, stream>>>((const ushort_t*)bufA, (ushort_t*)bufB);
    // attn_proj = ao @ ow^T  (8192 x 512, K=512), split-K=2 bf16 partials
    gemm_gll<0, 1, 2, 128><<<dim3(4, 64, 2), 256, 0, stream>>>(
        (const ushort_t*)bufB, wOW + (size_t)i * 262144, nullptr, bufC,
        DMODEL, DMODEL, DMODEL);
    resid_ln_sk<<<8192, 128, 0, stream>>>(h, (const ushort_t*)bufC, t_ob + i * DMODEL,
                                          t_ln1w + i * DMODEL, t_ln1b + i * DMODEL,
                                          h, h_bf, 0);
    // ff1 = relu(h @ l1w^T + l1b)  (8192 x 2048, K=512) -> bf16
    gemm_gll<1, 1, 1, 128><<<dim3(16, 64), 256, 0, stream>>>(
        h_bf, wL1 + (size_t)i * 1048576, t_l1b + i * DFF, bufA,
        DMODEL, DMODEL, DFF);
    // ff2 = ff1 @ l2w^T  (8192 x 512, K=2048), split-K=2 bf16 partials
    gemm_gll<0, 1, 2, 128><<<dim3(4, 64, 2), 256, 0, stream>>>(
        (const ushort_t*)bufA, wL2 + (size_t)i * 1048576, nullptr, bufC,
        DFF, DFF, DMODEL);
    resid_ln_sk<<<8192, 128, 0, stream>>>(h, (const ushort_t*)bufC, t_l2b + i * DMODEL,
                                          t_ln2w + i * DMODEL, t_ln2b + i * DMODEL,
                                          h, h_bf, 0);
  }

  // final LN -> d_out, then mean over L -> d_out tail
  float* out_h = (float*)d_out;
  resid_ln_kernel<<<8192, 128, 0, stream>>>(h, nullptr, no_w, no_b, out_h, nullptr);
  mean_part<<<128, 512, 0, stream>>>(out_h, bufF);
  mean_final<<<16, 256, 0, stream>>>(bufF, out_h + 4194304);
}